// Round 1
// baseline (285.616 us; speedup 1.0000x reference)
//
#include <hip/hip_runtime.h>
#include <hip/hip_bf16.h>

// ---------------------------------------------------------------------------
// HAttention1D: B=4 N=4096 DIM=1024 HEADS=8 DH=64 BSZ=16, 8 levels (0..7)
//  1) f2b: x, w_qkv, w_out -> bf16
//  2) gemm_qkv: 256x256 8-phase pipelined MFMA GEMM (counted vmcnt, raw
//     barriers, setprio, XOR-swizzled LDS), scatter epilogue into pyramids
//  3) pyramid_all: per-(bh,128-row-chunk) WG computes levels 1..7 in LDS
//  4) attn: ONE WAVE per 16x16 block, MFMA S^T=k.q^T then PV; y stored bf16
//  5) combine: U = sum_l y_l / (sum_l a_l + eps) -> bf16
//  6) gemm_out: same 256x256 8-phase GEMM, bias epilogue, f32 out
// ---------------------------------------------------------------------------

typedef __bf16 bf16x8 __attribute__((ext_vector_type(8)));
typedef float floatx4 __attribute__((ext_vector_type(4)));
typedef unsigned short ushortx8 __attribute__((ext_vector_type(8)));
typedef unsigned int uintx4 __attribute__((ext_vector_type(4)));

#define ROWS_PER_BH 8160  // 4096+2048+1024+512+256+128+64+32

__device__ __forceinline__ void g2lds16(const void* g, void* l) {
  __builtin_amdgcn_global_load_lds(
      (const __attribute__((address_space(1))) void*)g,
      (__attribute__((address_space(3))) void*)l, 16, 0, 0);
}

__device__ __forceinline__ unsigned short f2bu(float x) {
  __hip_bfloat16 h = __float2bfloat16(x);
  return *(unsigned short*)&h;
}
__device__ __forceinline__ float bu2f(unsigned short u) {
  __hip_bfloat16 h = *(__hip_bfloat16*)&u;
  return __bfloat162float(h);
}

// raw barrier (no vmcnt(0) drain) + compiler memory fence
__device__ __forceinline__ void wg_barrier() {
  asm volatile("" ::: "memory");
  __builtin_amdgcn_s_barrier();
  asm volatile("" ::: "memory");
}
__device__ __forceinline__ void lgk0() {
  asm volatile("s_waitcnt lgkmcnt(0)" ::: "memory");
}

// ---- fp32 -> bf16 convert, 4 elems/thread ---------------------------------
__global__ __launch_bounds__(256) void f2b_kernel(const float* __restrict__ s,
                                                  __hip_bfloat16* __restrict__ d,
                                                  int n) {
  int i0 = (blockIdx.x * 256 + threadIdx.x) * 4;
  if (i0 + 3 < n) {
    float4 v = *(const float4*)(s + i0);
    d[i0 + 0] = __float2bfloat16(v.x);
    d[i0 + 1] = __float2bfloat16(v.y);
    d[i0 + 2] = __float2bfloat16(v.z);
    d[i0 + 3] = __float2bfloat16(v.w);
  }
}

// ---------------------------------------------------------------------------
// 256x256 8-phase GEMM core. C = A[M,K] @ B[N,K]^T, bf16 in, f32 acc.
// 8 waves (2M x 4N), per-wave output 128x64 -> acc[8][4] (16x16 frags).
// LDS 128 KiB: dbuf x (A 256x64 + B 256x64) bf16. XOR swizzle: LDS chunk p
// (16B) of row r holds global chunk p^(r&7); staged via pre-swizzled global
// source (global_load_lds writes linearly), read back with the same XOR.
// Pipeline (group t computes K-tile t from buf[t&1], stages tile t+2):
//   ph0: ds_read B(8) + A quads 0,1 (8)            | MFMA quad0
//   ph1: ds_read A quads 2,3 (8); stage B0,B1(t+2) | MFMA quad1
//   ph2: stage A0(t+2)                             | MFMA quad2
//   ph3: stage A1(t+2); vmcnt(6) at group end      | MFMA quad3
// WAR safe: all reads of a region drain (lgkmcnt0) >=1 barrier before its
// overwriting stage is issued. RAW safe: vmcnt(6) at group end leaves only
// the newest 3 half-tiles in flight -> tile t+1 fully landed.
// ---------------------------------------------------------------------------
template <int K>
__device__ __forceinline__ void gemm256_core(const unsigned short* __restrict__ A,
                                             const unsigned short* __restrict__ B,
                                             unsigned short* lds, int tM, int tN,
                                             floatx4 acc[8][4]) {
  const int tid = threadIdx.x;
  const int lane = tid & 63;
  const int w = tid >> 6;
  const int wm = w >> 2, wn = w & 3;

  // staging coords: 8 threads/row, 64 rows per g2lds16 issue
  const int srow = tid >> 3;
  const int schunk = (tid & 7) ^ (srow & 7);  // pre-swizzled global chunk
  const unsigned short* Ab = A + (size_t)(tM + srow) * K + schunk * 8;
  const unsigned short* Bb = B + (size_t)(tN + srow) * K + schunk * 8;
  const int ltid8 = tid * 8;

  auto stage = [&](const unsigned short* gbase, unsigned short* lbase, int half, int kt) {
    const unsigned short* g = gbase + (size_t)(half * 128) * K + kt;
    unsigned short* l = lbase + half * 8192 + ltid8;
    g2lds16(g, l);
    g2lds16(g + (size_t)64 * K, l + 4096);
  };

  // prologue: tiles 0 and 1 (A0,A1,B0,B1 each)
  stage(Ab, lds, 0, 0); stage(Ab, lds, 1, 0);
  stage(Bb, lds + 16384, 0, 0); stage(Bb, lds + 16384, 1, 0);
  stage(Ab, lds + 32768, 0, 64); stage(Ab, lds + 32768, 1, 64);
  stage(Bb, lds + 49152, 0, 64); stage(Bb, lds + 49152, 1, 64);
  asm volatile("s_waitcnt vmcnt(8)" ::: "memory");  // tile 0 landed
  wg_barrier();

  const int frow = lane & 15, quad = lane >> 4, sw = frow & 7;
  const int arbase = (wm * 128 + frow) * 64;
  const int brbase = (wn * 64 + frow) * 64;
  const int NT = K / 64;

  for (int t = 0; t < NT; ++t) {
    unsigned short* lA = lds + ((t & 1) << 15);
    unsigned short* lB = lA + 16384;
    const int ktn = (t + 2) * 64;
    const bool st = (t + 2) < NT;

    // -------- phase 0: read all B frags + A quads 0,1
    bf16x8 bfr[4][2], a01[2][2][2];
#pragma unroll
    for (int nf = 0; nf < 4; nf++)
#pragma unroll
      for (int kk = 0; kk < 2; kk++)
        bfr[nf][kk] = *(const bf16x8*)&lB[brbase + nf * 1024 + (((kk * 4 + quad) ^ sw) * 8)];
#pragma unroll
    for (int q = 0; q < 2; q++)
#pragma unroll
      for (int mf2 = 0; mf2 < 2; mf2++)
#pragma unroll
        for (int kk = 0; kk < 2; kk++)
          a01[q][mf2][kk] = *(const bf16x8*)&lA[arbase + (q * 2 + mf2) * 1024 +
                                                (((kk * 4 + quad) ^ sw) * 8)];
    wg_barrier();
    lgk0();
    __builtin_amdgcn_s_setprio(1);
#pragma unroll
    for (int mf2 = 0; mf2 < 2; mf2++)
#pragma unroll
      for (int nf = 0; nf < 4; nf++)
#pragma unroll
        for (int kk = 0; kk < 2; kk++)
          acc[mf2][nf] = __builtin_amdgcn_mfma_f32_16x16x32_bf16(
              a01[0][mf2][kk], bfr[nf][kk], acc[mf2][nf], 0, 0, 0);
    __builtin_amdgcn_s_setprio(0);
    wg_barrier();

    // -------- phase 1: read A quads 2,3; stage B(t+2) into this buf
    bf16x8 a23[2][2][2];
#pragma unroll
    for (int q = 0; q < 2; q++)
#pragma unroll
      for (int mf2 = 0; mf2 < 2; mf2++)
#pragma unroll
        for (int kk = 0; kk < 2; kk++)
          a23[q][mf2][kk] = *(const bf16x8*)&lA[arbase + (4 + q * 2 + mf2) * 1024 +
                                                (((kk * 4 + quad) ^ sw) * 8)];
    if (st) { stage(Bb, lB, 0, ktn); stage(Bb, lB, 1, ktn); }
    wg_barrier();
    lgk0();
    __builtin_amdgcn_s_setprio(1);
#pragma unroll
    for (int mf2 = 0; mf2 < 2; mf2++)
#pragma unroll
      for (int nf = 0; nf < 4; nf++)
#pragma unroll
        for (int kk = 0; kk < 2; kk++)
          acc[2 + mf2][nf] = __builtin_amdgcn_mfma_f32_16x16x32_bf16(
              a01[1][mf2][kk], bfr[nf][kk], acc[2 + mf2][nf], 0, 0, 0);
    __builtin_amdgcn_s_setprio(0);
    wg_barrier();

    // -------- phase 2: stage A half0(t+2)
    if (st) stage(Ab, lA, 0, ktn);
    wg_barrier();
    __builtin_amdgcn_s_setprio(1);
#pragma unroll
    for (int mf2 = 0; mf2 < 2; mf2++)
#pragma unroll
      for (int nf = 0; nf < 4; nf++)
#pragma unroll
        for (int kk = 0; kk < 2; kk++)
          acc[4 + mf2][nf] = __builtin_amdgcn_mfma_f32_16x16x32_bf16(
              a23[0][mf2][kk], bfr[nf][kk], acc[4 + mf2][nf], 0, 0, 0);
    __builtin_amdgcn_s_setprio(0);
    wg_barrier();

    // -------- phase 3: stage A half1(t+2); counted vmcnt at group end
    if (st) stage(Ab, lA, 1, ktn);
    wg_barrier();
    __builtin_amdgcn_s_setprio(1);
#pragma unroll
    for (int mf2 = 0; mf2 < 2; mf2++)
#pragma unroll
      for (int nf = 0; nf < 4; nf++)
#pragma unroll
        for (int kk = 0; kk < 2; kk++)
          acc[6 + mf2][nf] = __builtin_amdgcn_mfma_f32_16x16x32_bf16(
              a23[1][mf2][kk], bfr[nf][kk], acc[6 + mf2][nf], 0, 0, 0);
    __builtin_amdgcn_s_setprio(0);
    if (st) asm volatile("s_waitcnt vmcnt(6)" ::: "memory");
    else    asm volatile("s_waitcnt vmcnt(0)" ::: "memory");
    wg_barrier();
  }
}

// ---- GEMM1: qkv = x[16384,1024] @ w_qkv[1536,1024]^T, scatter epilogue ----
__global__ __launch_bounds__(512, 2) void gemm_qkv_kernel(
    const unsigned short* __restrict__ A,   // xb [16384,1024] bf16
    const unsigned short* __restrict__ B,   // wqkvb [1536,1024] bf16
    __hip_bfloat16* __restrict__ qp, __hip_bfloat16* __restrict__ kp,
    __hip_bfloat16* __restrict__ vp) {
  __shared__ __align__(16) unsigned short lds[65536];  // 128 KiB
  const int lane = threadIdx.x & 63, w = threadIdx.x >> 6;
  const int wm = w >> 2, wn = w & 3;
  const int tM = blockIdx.x * 256, tN = blockIdx.y * 256;

  floatx4 acc[8][4];
#pragma unroll
  for (int i = 0; i < 8; i++)
#pragma unroll
    for (int j = 0; j < 4; j++) acc[i][j] = (floatx4){0.f, 0.f, 0.f, 0.f};

  gemm256_core<1024>(A, B, lds, tM, tN, acc);

  // epilogue: C/D layout col=lane&15, row=(lane>>4)*4+r  [verified m89]
  // wave's 64-col range never crosses a 512-col tensor boundary -> uniform
  const int quad = lane >> 4, m15 = lane & 15;
  const int cbase = tN + wn * 64;
  const int tensor = cbase >> 9;          // 0=q 1=k 2=v
  const int h = (cbase & 511) >> 6;
  __hip_bfloat16* dstbuf = (tensor == 0) ? qp : ((tensor == 1) ? kp : vp);
  const float scale = (tensor == 0) ? 0.125f : 1.0f;  // DH^-0.5
#pragma unroll
  for (int mf = 0; mf < 8; mf++) {
#pragma unroll
    for (int nf = 0; nf < 4; nf++) {
#pragma unroll
      for (int r = 0; r < 4; r++) {
        const int m = tM + wm * 128 + mf * 16 + quad * 4 + r;
        const int b = m >> 12, n = m & 4095;
        dstbuf[((size_t)(b * 8 + h) * ROWS_PER_BH + n) * 64 + nf * 16 + m15] =
            __float2bfloat16(acc[mf][nf][r] * scale);
      }
    }
  }
}

// ---- GEMM2: out = U[16384,512] @ w_out[1024,512]^T + b_out ----------------
__global__ __launch_bounds__(512, 2) void gemm_out_kernel(
    const unsigned short* __restrict__ A,   // Ub [16384,512] bf16
    const unsigned short* __restrict__ B,   // wob [1024,512] bf16
    const float* __restrict__ bias, float* __restrict__ out) {
  __shared__ __align__(16) unsigned short lds[65536];
  const int lane = threadIdx.x & 63, w = threadIdx.x >> 6;
  const int wm = w >> 2, wn = w & 3;
  const int tM = blockIdx.x * 256, tN = blockIdx.y * 256;

  floatx4 acc[8][4];
#pragma unroll
  for (int i = 0; i < 8; i++)
#pragma unroll
    for (int j = 0; j < 4; j++) acc[i][j] = (floatx4){0.f, 0.f, 0.f, 0.f};

  gemm256_core<512>(A, B, lds, tM, tN, acc);

  const int quad = lane >> 4, m15 = lane & 15;
#pragma unroll
  for (int mf = 0; mf < 8; mf++) {
#pragma unroll
    for (int nf = 0; nf < 4; nf++) {
      const int c = tN + wn * 64 + nf * 16 + m15;
      const float bb = bias[c];
#pragma unroll
      for (int r = 0; r < 4; r++) {
        const int m = tM + wm * 128 + mf * 16 + quad * 4 + r;
        out[(size_t)m * 1024 + c] = acc[mf][nf][r] + bb;
      }
    }
  }
}

// ---- pyramid, single kernel: WG = (bh, 128-row chunk), levels 1..7 --------
__global__ __launch_bounds__(256) void pyramid_all_kernel(
    __hip_bfloat16* __restrict__ qp, __hip_bfloat16* __restrict__ kp,
    __hip_bfloat16* __restrict__ vp) {
  __shared__ unsigned short qs[128 * 64], ks[128 * 64], vs[128 * 64];  // 48 KB
  const int bh = blockIdx.x >> 5;
  const int chunk = blockIdx.x & 31;
  const int tid = threadIdx.x;
  const size_t base = (size_t)bh * ROWS_PER_BH;
  const size_t g0 = (base + chunk * 128) * 64;
  const unsigned short* qg = (const unsigned short*)qp;
  const unsigned short* kg = (const unsigned short*)kp;
  const unsigned short* vg = (const unsigned short*)vp;
#pragma unroll
  for (int c = 0; c < 4; c++) {
    int off = c * 2048 + tid * 8;
    *(ushortx8*)&qs[off] = *(const ushortx8*)(qg + g0 + off);
    *(ushortx8*)&ks[off] = *(const ushortx8*)(kg + g0 + off);
    *(ushortx8*)&vs[off] = *(const ushortx8*)(vg + g0 + off);
  }
  const int offs[8] = {0, 4096, 6144, 7168, 7680, 7936, 8064, 8128};
#pragma unroll
  for (int l = 1; l <= 7; l++) {
    __syncthreads();
    const int nOut = 128 >> l;
    for (int e = tid; e < nOut * 32; e += 256) {
      const int i = e >> 5, dp = (e & 31) * 2;
      const int a = (i << l) * 64 + dp;
      const int b = a + (1 << (l - 1)) * 64;
      unsigned short q0 = f2bu(0.5f * (bu2f(qs[a]) + bu2f(qs[b])));
      unsigned short q1 = f2bu(0.5f * (bu2f(qs[a + 1]) + bu2f(qs[b + 1])));
      unsigned short k0 = f2bu(0.5f * (bu2f(ks[a]) + bu2f(ks[b])));
      unsigned short k1 = f2bu(0.5f * (bu2f(ks[a + 1]) + bu2f(ks[b + 1])));
      unsigned short v0 = f2bu(bu2f(vs[a]) + bu2f(vs[b]));
      unsigned short v1 = f2bu(bu2f(vs[a + 1]) + bu2f(vs[b + 1]));
      qs[a] = q0; qs[a + 1] = q1;
      ks[a] = k0; ks[a + 1] = k1;
      vs[a] = v0; vs[a + 1] = v1;
      const size_t grow = (base + offs[l] + (size_t)chunk * nOut + i) * 64 + dp;
      *(unsigned int*)((unsigned short*)qp + grow) = (unsigned int)q0 | ((unsigned int)q1 << 16);
      *(unsigned int*)((unsigned short*)kp + grow) = (unsigned int)k0 | ((unsigned int)k1 << 16);
      *(unsigned int*)((unsigned short*)vp + grow) = (unsigned int)v0 | ((unsigned int)v1 << 16);
    }
  }
}

// ---- block attention: ONE WAVE per (level-block, bh), MFMA, no barriers ---
__global__ __launch_bounds__(256) void attn_kernel(
    const unsigned short* __restrict__ qp, const unsigned short* __restrict__ kp,
    const unsigned short* __restrict__ vp, __hip_bfloat16* __restrict__ yall,
    float* __restrict__ aall) {
  __shared__ __align__(16) unsigned short vT[4][64 * 24];  // per-wave slice, stride 24
  const int w = threadIdx.x >> 6, lane = threadIdx.x & 63;
  const int g = blockIdx.x * 4 + w;
  if (g >= 510) return;
  const int bh = blockIdx.y;
  int level, blk;
  if (g < 256)      { level = 0; blk = g; }
  else if (g < 384) { level = 1; blk = g - 256; }
  else if (g < 448) { level = 2; blk = g - 384; }
  else if (g < 480) { level = 3; blk = g - 448; }
  else if (g < 496) { level = 4; blk = g - 480; }
  else if (g < 504) { level = 5; blk = g - 496; }
  else if (g < 508) { level = 6; blk = g - 504; }
  else              { level = 7; blk = g - 508; }
  const int ro = 8192 - (8192 >> level);
  const int kblk = (level == 0) ? blk : (blk ^ 1);  // sibling key flip (v NOT flipped)
  const int m = lane & 15, q = lane >> 4;
  const size_t qbase = ((size_t)bh * ROWS_PER_BH + ro + blk * 16) * 64;
  const size_t kbase = ((size_t)bh * ROWS_PER_BH + ro + kblk * 16) * 64;

  // fragment loads: A-op = k rows, B-op = q rows (both contiguous 8 bf16)
  const bf16x8 ka0 = *(const bf16x8*)(kp + kbase + m * 64 + q * 8);
  const bf16x8 ka1 = *(const bf16x8*)(kp + kbase + m * 64 + 32 + q * 8);
  const bf16x8 qb0 = *(const bf16x8*)(qp + qbase + m * 64 + q * 8);
  const bf16x8 qb1 = *(const bf16x8*)(qp + qbase + m * 64 + 32 + q * 8);

  // stage v transposed into LDS: vT[d][vrow], row stride 24
  const ushortx8 v0 = *(const ushortx8*)(vp + qbase + m * 64 + q * 16);
  const ushortx8 v1 = *(const ushortx8*)(vp + qbase + m * 64 + q * 16 + 8);
  unsigned short* vtw = vT[w];
#pragma unroll
  for (int j = 0; j < 8; j++) vtw[(q * 16 + j) * 24 + m] = v0[j];
#pragma unroll
  for (int j = 0; j < 8; j++) vtw[(q * 16 + 8 + j) * 24 + m] = v1[j];

  // S^T: D[j=quad*4+r][i=lane&15] = sum_d k[j][d] q[i][d]
  floatx4 s = (floatx4){0.f, 0.f, 0.f, 0.f};
  s = __builtin_amdgcn_mfma_f32_16x16x32_bf16(ka0, qb0, s, 0, 0, 0);
  s = __builtin_amdgcn_mfma_f32_16x16x32_bf16(ka1, qb1, s, 0, 0, 0);

  // P = exp(S) in bf16 (numerator & denominator use the SAME rounded values)
  unsigned short pb0 = f2bu(__expf(s[0])), pb1 = f2bu(__expf(s[1]));
  unsigned short pb2 = f2bu(__expf(s[2])), pb3 = f2bu(__expf(s[3]));
  float asum = bu2f(pb0) + bu2f(pb1) + bu2f(pb2) + bu2f(pb3);
  asum += __shfl_xor(asum, 16, 64);
  asum += __shfl_xor(asum, 32, 64);
  const size_t arow = (size_t)bh * ROWS_PER_BH + ro + blk * 16;
  if (q == 0) aall[arow + m] = asum;

  // A-fragment for PV: lane (m,q<2) needs P[m][8q..8q+7] from lanes m+32q, m+32q+16
  unsigned int d0 = (unsigned int)pb0 | ((unsigned int)pb1 << 16);
  unsigned int d1 = (unsigned int)pb2 | ((unsigned int)pb3 << 16);
  const int s0l = m + 32 * (q & 1);
  unsigned int u0 = __shfl(d0, s0l, 64);
  unsigned int u1 = __shfl(d1, s0l, 64);
  unsigned int u2 = __shfl(d0, s0l + 16, 64);
  unsigned int u3 = __shfl(d1, s0l + 16, 64);
  union { uintx4 i; bf16x8 b; } pau;
  pau.i = (q < 2) ? (uintx4){u0, u1, u2, u3} : (uintx4){0u, 0u, 0u, 0u};
  const bf16x8 pa = pau.b;

  // Y = P . v, 4 column chunks of 16; K padded to 32 with zeros
#pragma unroll
  for (int c = 0; c < 4; c++) {
    union { uintx4 i; bf16x8 b; } bvu;
    bvu.i = (uintx4){0u, 0u, 0u, 0u};
    if (q < 2) bvu.b = *(const bf16x8*)&vtw[(c * 16 + m) * 24 + q * 8];
    floatx4 y = (floatx4){0.f, 0.f, 0.f, 0.f};
    y = __builtin_amdgcn_mfma_f32_16x16x32_bf16(pa, bvu.b, y, 0, 0, 0);
#pragma unroll
    for (int r = 0; r < 4; r++)
      yall[(arow + q * 4 + r) * 64 + c * 16 + m] = __float2bfloat16(y[r]);
  }
}

// ---- combine: U = sum_l y_l[i>>l] / (sum_l a_l[i>>l] + eps) ---------------
__global__ __launch_bounds__(256) void combine_kernel(
    const unsigned short* __restrict__ yall, const float* __restrict__ aall,
    __hip_bfloat16* __restrict__ Ub) {
  int idx = blockIdx.x * 256 + threadIdx.x;  // 32*4096*64
  int d = idx & 63;
  int i = (idx >> 6) & 4095;
  int bh = idx >> 18;
  size_t base = (size_t)bh * ROWS_PER_BH;
  float Y = 0.f, Aa = 0.f;
#pragma unroll
  for (int l = 0; l < 8; l++) {
    int r = (8192 - (8192 >> l)) + (i >> l);
    Y += bu2f(yall[(base + r) * 64 + d]);
    Aa += aall[base + r];
  }
  float u = Y / (Aa + 1e-8f);
  int b = bh >> 3, h = bh & 7;
  size_t m = (size_t)b * 4096 + i;
  Ub[m * 512 + (size_t)h * 64 + d] = __float2bfloat16(u);
}

// ---------------------------------------------------------------------------
extern "C" void kernel_launch(void* const* d_in, const int* in_sizes, int n_in,
                              void* d_out, int out_size, void* d_ws, size_t ws_size,
                              hipStream_t stream) {
  const float* x     = (const float*)d_in[0];  // [4,4096,1024]
  const float* w_qkv = (const float*)d_in[1];  // [1536,1024]
  const float* w_out = (const float*)d_in[2];  // [1024,512]
  const float* b_out = (const float*)d_in[3];  // [1024]
  float* out = (float*)d_out;

  char* ws = (char*)d_ws;
  __hip_bfloat16* xb    = (__hip_bfloat16*)(ws + 0);           // 33554432 B
  __hip_bfloat16* wqkvb = (__hip_bfloat16*)(ws + 33554432);    //  3145728 B
  __hip_bfloat16* wob   = (__hip_bfloat16*)(ws + 36700160);    //  1048576 B
  __hip_bfloat16* qp    = (__hip_bfloat16*)(ws + 37748736);    // 33423360 B
  __hip_bfloat16* kp    = (__hip_bfloat16*)(ws + 71172096);    // 33423360 B
  __hip_bfloat16* vp    = (__hip_bfloat16*)(ws + 104595456);   // 33423360 B
  __hip_bfloat16* yall  = (__hip_bfloat16*)(ws + 138018816);   // 33423360 B
  float* aall           = (float*)(ws + 171442176);            //  1044480 B
  __hip_bfloat16* Ub    = (__hip_bfloat16*)(ws + 172486656);   // 16777216 B

  // 1) converts
  f2b_kernel<<<16384, 256, 0, stream>>>(x, xb, 16777216);
  f2b_kernel<<<1536, 256, 0, stream>>>(w_qkv, wqkvb, 1572864);
  f2b_kernel<<<512, 256, 0, stream>>>(w_out, wob, 524288);

  // 2) qkv projection + scatter (256x256 tiles: 64 x 6 blocks, 512 thr)
  gemm_qkv_kernel<<<dim3(64, 6), 512, 0, stream>>>(
      (const unsigned short*)xb, (const unsigned short*)wqkvb, qp, kp, vp);

  // 3) pyramid levels 1..7, single launch
  pyramid_all_kernel<<<1024, 256, 0, stream>>>(qp, kp, vp);

  // 4) block attention over all levels (1 wave / block, 4 waves / wg)
  attn_kernel<<<dim3(128, 32), 256, 0, stream>>>(
      (const unsigned short*)qp, (const unsigned short*)kp,
      (const unsigned short*)vp, yall, aall);

  // 5) combine to U (bf16)
  combine_kernel<<<32768, 256, 0, stream>>>((const unsigned short*)yall, aall, Ub);

  // 6) out projection + bias (256x256 tiles: 64 x 4 blocks)
  gemm_out_kernel<<<dim3(64, 4), 512, 0, stream>>>(
      (const unsigned short*)Ub, (const unsigned short*)wob, b_out, out);
}

// Round 2
// 283.782 us; speedup vs baseline: 1.0065x; 1.0065x over previous
//
#include <hip/hip_runtime.h>
#include <hip/hip_bf16.h>

// ---------------------------------------------------------------------------
// HAttention1D: B=4 N=4096 DIM=1024 HEADS=8 DH=64 BSZ=16, 8 levels (0..7)
//  1) f2b: x, w_qkv, w_out -> bf16
//  2) gemm_qkv: 256x256 kk-split 8-phase MFMA GEMM (reads 8/4/8/4 per tile,
//     1 half-tile stage per early phase, counted vmcnt(4), raw barriers,
//     setprio, XOR-swizzled LDS), scatter epilogue into pyramids
//  3) pyramid_all: per-(bh,128-row-chunk) WG computes levels 1..7 in LDS
//  4) attn: ONE WAVE per 16x16 block, MFMA S^T=k.q^T then PV; y stored bf16
//  5) combine: U = sum_l y_l / (sum_l a_l + eps) -> bf16
//  6) gemm_out: same GEMM core, bias epilogue, f32 out
// ---------------------------------------------------------------------------

typedef __bf16 bf16x8 __attribute__((ext_vector_type(8)));
typedef float floatx4 __attribute__((ext_vector_type(4)));
typedef unsigned short ushortx8 __attribute__((ext_vector_type(8)));
typedef unsigned int uintx4 __attribute__((ext_vector_type(4)));

#define ROWS_PER_BH 8160  // 4096+2048+1024+512+256+128+64+32

__device__ __forceinline__ void g2lds16(const void* g, void* l) {
  __builtin_amdgcn_global_load_lds(
      (const __attribute__((address_space(1))) void*)g,
      (__attribute__((address_space(3))) void*)l, 16, 0, 0);
}

__device__ __forceinline__ unsigned short f2bu(float x) {
  __hip_bfloat16 h = __float2bfloat16(x);
  return *(unsigned short*)&h;
}
__device__ __forceinline__ float bu2f(unsigned short u) {
  __hip_bfloat16 h = *(__hip_bfloat16*)&u;
  return __bfloat162float(h);
}

// raw barrier (no vmcnt(0) drain) + compiler memory fence
__device__ __forceinline__ void wg_barrier() {
  asm volatile("" ::: "memory");
  __builtin_amdgcn_s_barrier();
  asm volatile("" ::: "memory");
}
__device__ __forceinline__ void lgk0() {
  asm volatile("s_waitcnt lgkmcnt(0)" ::: "memory");
}

// ---- fp32 -> bf16 convert, 4 elems/thread ---------------------------------
__global__ __launch_bounds__(256) void f2b_kernel(const float* __restrict__ s,
                                                  __hip_bfloat16* __restrict__ d,
                                                  int n) {
  int i0 = (blockIdx.x * 256 + threadIdx.x) * 4;
  if (i0 + 3 < n) {
    float4 v = *(const float4*)(s + i0);
    d[i0 + 0] = __float2bfloat16(v.x);
    d[i0 + 1] = __float2bfloat16(v.y);
    d[i0 + 2] = __float2bfloat16(v.z);
    d[i0 + 3] = __float2bfloat16(v.w);
  }
}

// ---------------------------------------------------------------------------
// 256x256 GEMM core, kk-split 4-phase schedule. C = A[M,K] @ B[N,K]^T.
// 8 waves (2M x 4N), per-wave output 128x64 -> acc[8][4] (16x16 frags).
// LDS 128 KiB: dbuf x (A 256x64 + B 256x64) bf16, XOR-swizzled via
// pre-swizzled global source (global_load_lds writes linearly).
// Per K-tile t (buf b=t&1), phases (each: reads; stage; barrier; lgkmcnt0;
// setprio1; 16 MFMA; setprio0; barrier):
//   ph0: read B.kk0(4) + A.mf0-3.kk0(4); stage A-half0(t+1) -> buf b^1
//   ph1: read A.mf4-7.kk0(4)  [B regs reused]; stage A-half1(t+1) -> buf b^1
//   ph2: read B.kk1(4) + A.mf0-3.kk1(4); no stage
//   ph3: read A.mf4-7.kk1(4); stage B-half0+1(t+2) -> buf b; vmcnt(4)
// WAR: A(buf b^1) last read at t-1.ph3 (drained) before t.ph0 stage; B(buf b)
// last read at t.ph2 (drained) before t.ph3 stage.  RAW: vmcnt(4) at t.ph3
// keeps only B(t+2)'s 4 loads in flight -> all of tile t+1 landed; the
// waited-on loads (A1(t+1), staged t.ph1) are ~2 phases (~1600 cyc) old.
// ---------------------------------------------------------------------------
template <int K>
__device__ __forceinline__ void gemm256_core(const unsigned short* __restrict__ A,
                                             const unsigned short* __restrict__ B,
                                             unsigned short* lds, int tM, int tN,
                                             floatx4 acc[8][4]) {
  const int tid = threadIdx.x;
  const int lane = tid & 63;
  const int w = tid >> 6;
  const int wm = w >> 2, wn = w & 3;

  // staging coords: 8 threads/row, 64 rows per g2lds16 issue
  const int srow = tid >> 3;
  const int schunk = (tid & 7) ^ (srow & 7);  // pre-swizzled global chunk
  const unsigned short* Ab = A + (size_t)(tM + srow) * K + schunk * 8;
  const unsigned short* Bb = B + (size_t)(tN + srow) * K + schunk * 8;
  const int ltid8 = tid * 8;

  auto stage = [&](const unsigned short* gbase, unsigned short* lbase, int half, int kt) {
    const unsigned short* g = gbase + (size_t)(half * 128) * K + kt;
    unsigned short* l = lbase + half * 8192 + ltid8;
    g2lds16(g, l);
    g2lds16(g + (size_t)64 * K, l + 4096);
  };

  // prologue: tile0 (A+B) -> buf0; B(tile1) -> buf1. vmcnt(4) = tile0 landed.
  stage(Ab, lds, 0, 0); stage(Ab, lds, 1, 0);
  stage(Bb, lds + 16384, 0, 0); stage(Bb, lds + 16384, 1, 0);
  stage(Bb, lds + 49152, 0, 64); stage(Bb, lds + 49152, 1, 64);
  asm volatile("s_waitcnt vmcnt(4)" ::: "memory");
  wg_barrier();

  const int frow = lane & 15, quad = lane >> 4, sw = frow & 7;
  const int arbase = (wm * 128 + frow) * 64;
  const int brbase = (wn * 64 + frow) * 64;
  const int c0 = (quad ^ sw) * 8;        // kk0 chunk byte-position
  const int c1 = ((4 + quad) ^ sw) * 8;  // kk1 chunk byte-position
  const int NT = K / 64;

  for (int t = 0; t < NT; ++t) {
    unsigned short* lA = lds + ((t & 1) << 15);
    unsigned short* lB = lA + 16384;
    unsigned short* nA = lds + (((t + 1) & 1) << 15);
    const bool stA = (t + 1) < NT;
    const bool stB = (t + 2) < NT;
    const int ktA = (t + 1) * 64, ktB = (t + 2) * 64;

    bf16x8 bfr[4], af[4], ag[4];

    // -------- ph0: B kk0 + A mf0-3 kk0; stage A-half0(t+1)
#pragma unroll
    for (int nf = 0; nf < 4; nf++)
      bfr[nf] = *(const bf16x8*)&lB[brbase + nf * 1024 + c0];
#pragma unroll
    for (int mf = 0; mf < 4; mf++)
      af[mf] = *(const bf16x8*)&lA[arbase + mf * 1024 + c0];
    if (stA) stage(Ab, nA, 0, ktA);
    wg_barrier();
    lgk0();
    __builtin_amdgcn_s_setprio(1);
#pragma unroll
    for (int mf = 0; mf < 4; mf++)
#pragma unroll
      for (int nf = 0; nf < 4; nf++)
        acc[mf][nf] = __builtin_amdgcn_mfma_f32_16x16x32_bf16(
            af[mf], bfr[nf], acc[mf][nf], 0, 0, 0);
    __builtin_amdgcn_s_setprio(0);
    wg_barrier();

    // -------- ph1: A mf4-7 kk0 (B regs reused); stage A-half1(t+1)
#pragma unroll
    for (int mf = 0; mf < 4; mf++)
      ag[mf] = *(const bf16x8*)&lA[arbase + (4 + mf) * 1024 + c0];
    if (stA) stage(Ab, nA, 1, ktA);
    wg_barrier();
    lgk0();
    __builtin_amdgcn_s_setprio(1);
#pragma unroll
    for (int mf = 0; mf < 4; mf++)
#pragma unroll
      for (int nf = 0; nf < 4; nf++)
        acc[4 + mf][nf] = __builtin_amdgcn_mfma_f32_16x16x32_bf16(
            ag[mf], bfr[nf], acc[4 + mf][nf], 0, 0, 0);
    __builtin_amdgcn_s_setprio(0);
    wg_barrier();

    // -------- ph2: B kk1 + A mf0-3 kk1; no stage
#pragma unroll
    for (int nf = 0; nf < 4; nf++)
      bfr[nf] = *(const bf16x8*)&lB[brbase + nf * 1024 + c1];
#pragma unroll
    for (int mf = 0; mf < 4; mf++)
      af[mf] = *(const bf16x8*)&lA[arbase + mf * 1024 + c1];
    wg_barrier();
    lgk0();
    __builtin_amdgcn_s_setprio(1);
#pragma unroll
    for (int mf = 0; mf < 4; mf++)
#pragma unroll
      for (int nf = 0; nf < 4; nf++)
        acc[mf][nf] = __builtin_amdgcn_mfma_f32_16x16x32_bf16(
            af[mf], bfr[nf], acc[mf][nf], 0, 0, 0);
    __builtin_amdgcn_s_setprio(0);
    wg_barrier();

    // -------- ph3: A mf4-7 kk1; stage B both halves(t+2); counted vmcnt
#pragma unroll
    for (int mf = 0; mf < 4; mf++)
      ag[mf] = *(const bf16x8*)&lA[arbase + (4 + mf) * 1024 + c1];
    if (stB) {
      stage(Bb, lB, 0, ktB);
      stage(Bb, lB, 1, ktB);
      asm volatile("s_waitcnt vmcnt(4)" ::: "memory");
    } else {
      asm volatile("s_waitcnt vmcnt(0)" ::: "memory");
    }
    wg_barrier();
    lgk0();
    __builtin_amdgcn_s_setprio(1);
#pragma unroll
    for (int mf = 0; mf < 4; mf++)
#pragma unroll
      for (int nf = 0; nf < 4; nf++)
        acc[4 + mf][nf] = __builtin_amdgcn_mfma_f32_16x16x32_bf16(
            ag[mf], bfr[nf], acc[4 + mf][nf], 0, 0, 0);
    __builtin_amdgcn_s_setprio(0);
    wg_barrier();
  }
}

// ---- GEMM1: qkv = x[16384,1024] @ w_qkv[1536,1024]^T, scatter epilogue ----
__global__ __launch_bounds__(512, 2) void gemm_qkv_kernel(
    const unsigned short* __restrict__ A,   // xb [16384,1024] bf16
    const unsigned short* __restrict__ B,   // wqkvb [1536,1024] bf16
    __hip_bfloat16* __restrict__ qp, __hip_bfloat16* __restrict__ kp,
    __hip_bfloat16* __restrict__ vp) {
  __shared__ __align__(16) unsigned short lds[65536];  // 128 KiB
  const int lane = threadIdx.x & 63, w = threadIdx.x >> 6;
  const int wm = w >> 2, wn = w & 3;
  const int tM = blockIdx.x * 256, tN = blockIdx.y * 256;

  floatx4 acc[8][4];
#pragma unroll
  for (int i = 0; i < 8; i++)
#pragma unroll
    for (int j = 0; j < 4; j++) acc[i][j] = (floatx4){0.f, 0.f, 0.f, 0.f};

  gemm256_core<1024>(A, B, lds, tM, tN, acc);

  // epilogue: C/D layout col=lane&15, row=(lane>>4)*4+r  [verified m89]
  // wave's 64-col range never crosses a 512-col tensor boundary -> uniform
  const int quad = lane >> 4, m15 = lane & 15;
  const int cbase = tN + wn * 64;
  const int tensor = cbase >> 9;          // 0=q 1=k 2=v
  const int h = (cbase & 511) >> 6;
  __hip_bfloat16* dstbuf = (tensor == 0) ? qp : ((tensor == 1) ? kp : vp);
  const float scale = (tensor == 0) ? 0.125f : 1.0f;  // DH^-0.5
#pragma unroll
  for (int mf = 0; mf < 8; mf++) {
#pragma unroll
    for (int nf = 0; nf < 4; nf++) {
#pragma unroll
      for (int r = 0; r < 4; r++) {
        const int m = tM + wm * 128 + mf * 16 + quad * 4 + r;
        const int b = m >> 12, n = m & 4095;
        dstbuf[((size_t)(b * 8 + h) * ROWS_PER_BH + n) * 64 + nf * 16 + m15] =
            __float2bfloat16(acc[mf][nf][r] * scale);
      }
    }
  }
}

// ---- GEMM2: out = U[16384,512] @ w_out[1024,512]^T + b_out ----------------
__global__ __launch_bounds__(512, 2) void gemm_out_kernel(
    const unsigned short* __restrict__ A,   // Ub [16384,512] bf16
    const unsigned short* __restrict__ B,   // wob [1024,512] bf16
    const float* __restrict__ bias, float* __restrict__ out) {
  __shared__ __align__(16) unsigned short lds[65536];
  const int lane = threadIdx.x & 63, w = threadIdx.x >> 6;
  const int wm = w >> 2, wn = w & 3;
  const int tM = blockIdx.x * 256, tN = blockIdx.y * 256;

  floatx4 acc[8][4];
#pragma unroll
  for (int i = 0; i < 8; i++)
#pragma unroll
    for (int j = 0; j < 4; j++) acc[i][j] = (floatx4){0.f, 0.f, 0.f, 0.f};

  gemm256_core<512>(A, B, lds, tM, tN, acc);

  const int quad = lane >> 4, m15 = lane & 15;
#pragma unroll
  for (int mf = 0; mf < 8; mf++) {
#pragma unroll
    for (int nf = 0; nf < 4; nf++) {
      const int c = tN + wn * 64 + nf * 16 + m15;
      const float bb = bias[c];
#pragma unroll
      for (int r = 0; r < 4; r++) {
        const int m = tM + wm * 128 + mf * 16 + quad * 4 + r;
        out[(size_t)m * 1024 + c] = acc[mf][nf][r] + bb;
      }
    }
  }
}

// ---- pyramid, single kernel: WG = (bh, 128-row chunk), levels 1..7 --------
__global__ __launch_bounds__(256) void pyramid_all_kernel(
    __hip_bfloat16* __restrict__ qp, __hip_bfloat16* __restrict__ kp,
    __hip_bfloat16* __restrict__ vp) {
  __shared__ unsigned short qs[128 * 64], ks[128 * 64], vs[128 * 64];  // 48 KB
  const int bh = blockIdx.x >> 5;
  const int chunk = blockIdx.x & 31;
  const int tid = threadIdx.x;
  const size_t base = (size_t)bh * ROWS_PER_BH;
  const size_t g0 = (base + chunk * 128) * 64;
  const unsigned short* qg = (const unsigned short*)qp;
  const unsigned short* kg = (const unsigned short*)kp;
  const unsigned short* vg = (const unsigned short*)vp;
#pragma unroll
  for (int c = 0; c < 4; c++) {
    int off = c * 2048 + tid * 8;
    *(ushortx8*)&qs[off] = *(const ushortx8*)(qg + g0 + off);
    *(ushortx8*)&ks[off] = *(const ushortx8*)(kg + g0 + off);
    *(ushortx8*)&vs[off] = *(const ushortx8*)(vg + g0 + off);
  }
  const int offs[8] = {0, 4096, 6144, 7168, 7680, 7936, 8064, 8128};
#pragma unroll
  for (int l = 1; l <= 7; l++) {
    __syncthreads();
    const int nOut = 128 >> l;
    for (int e = tid; e < nOut * 32; e += 256) {
      const int i = e >> 5, dp = (e & 31) * 2;
      const int a = (i << l) * 64 + dp;
      const int b = a + (1 << (l - 1)) * 64;
      unsigned short q0 = f2bu(0.5f * (bu2f(qs[a]) + bu2f(qs[b])));
      unsigned short q1 = f2bu(0.5f * (bu2f(qs[a + 1]) + bu2f(qs[b + 1])));
      unsigned short k0 = f2bu(0.5f * (bu2f(ks[a]) + bu2f(ks[b])));
      unsigned short k1 = f2bu(0.5f * (bu2f(ks[a + 1]) + bu2f(ks[b + 1])));
      unsigned short v0 = f2bu(bu2f(vs[a]) + bu2f(vs[b]));
      unsigned short v1 = f2bu(bu2f(vs[a + 1]) + bu2f(vs[b + 1]));
      qs[a] = q0; qs[a + 1] = q1;
      ks[a] = k0; ks[a + 1] = k1;
      vs[a] = v0; vs[a + 1] = v1;
      const size_t grow = (base + offs[l] + (size_t)chunk * nOut + i) * 64 + dp;
      *(unsigned int*)((unsigned short*)qp + grow) = (unsigned int)q0 | ((unsigned int)q1 << 16);
      *(unsigned int*)((unsigned short*)kp + grow) = (unsigned int)k0 | ((unsigned int)k1 << 16);
      *(unsigned int*)((unsigned short*)vp + grow) = (unsigned int)v0 | ((unsigned int)v1 << 16);
    }
  }
}

// ---- block attention: ONE WAVE per (level-block, bh), MFMA, no barriers ---
__global__ __launch_bounds__(256) void attn_kernel(
    const unsigned short* __restrict__ qp, const unsigned short* __restrict__ kp,
    const unsigned short* __restrict__ vp, __hip_bfloat16* __restrict__ yall,
    float* __restrict__ aall) {
  __shared__ __align__(16) unsigned short vT[4][64 * 24];  // per-wave slice, stride 24
  const int w = threadIdx.x >> 6, lane = threadIdx.x & 63;
  const int g = blockIdx.x * 4 + w;
  if (g >= 510) return;
  const int bh = blockIdx.y;
  int level, blk;
  if (g < 256)      { level = 0; blk = g; }
  else if (g < 384) { level = 1; blk = g - 256; }
  else if (g < 448) { level = 2; blk = g - 384; }
  else if (g < 480) { level = 3; blk = g - 448; }
  else if (g < 496) { level = 4; blk = g - 480; }
  else if (g < 504) { level = 5; blk = g - 496; }
  else if (g < 508) { level = 6; blk = g - 504; }
  else              { level = 7; blk = g - 508; }
  const int ro = 8192 - (8192 >> level);
  const int kblk = (level == 0) ? blk : (blk ^ 1);  // sibling key flip (v NOT flipped)
  const int m = lane & 15, q = lane >> 4;
  const size_t qbase = ((size_t)bh * ROWS_PER_BH + ro + blk * 16) * 64;
  const size_t kbase = ((size_t)bh * ROWS_PER_BH + ro + kblk * 16) * 64;

  // fragment loads: A-op = k rows, B-op = q rows (both contiguous 8 bf16)
  const bf16x8 ka0 = *(const bf16x8*)(kp + kbase + m * 64 + q * 8);
  const bf16x8 ka1 = *(const bf16x8*)(kp + kbase + m * 64 + 32 + q * 8);
  const bf16x8 qb0 = *(const bf16x8*)(qp + qbase + m * 64 + q * 8);
  const bf16x8 qb1 = *(const bf16x8*)(qp + qbase + m * 64 + 32 + q * 8);

  // stage v transposed into LDS: vT[d][vrow], row stride 24
  const ushortx8 v0 = *(const ushortx8*)(vp + qbase + m * 64 + q * 16);
  const ushortx8 v1 = *(const ushortx8*)(vp + qbase + m * 64 + q * 16 + 8);
  unsigned short* vtw = vT[w];
#pragma unroll
  for (int j = 0; j < 8; j++) vtw[(q * 16 + j) * 24 + m] = v0[j];
#pragma unroll
  for (int j = 0; j < 8; j++) vtw[(q * 16 + 8 + j) * 24 + m] = v1[j];

  // S^T: D[j=quad*4+r][i=lane&15] = sum_d k[j][d] q[i][d]
  floatx4 s = (floatx4){0.f, 0.f, 0.f, 0.f};
  s = __builtin_amdgcn_mfma_f32_16x16x32_bf16(ka0, qb0, s, 0, 0, 0);
  s = __builtin_amdgcn_mfma_f32_16x16x32_bf16(ka1, qb1, s, 0, 0, 0);

  // P = exp(S) in bf16 (numerator & denominator use the SAME rounded values)
  unsigned short pb0 = f2bu(__expf(s[0])), pb1 = f2bu(__expf(s[1]));
  unsigned short pb2 = f2bu(__expf(s[2])), pb3 = f2bu(__expf(s[3]));
  float asum = bu2f(pb0) + bu2f(pb1) + bu2f(pb2) + bu2f(pb3);
  asum += __shfl_xor(asum, 16, 64);
  asum += __shfl_xor(asum, 32, 64);
  const size_t arow = (size_t)bh * ROWS_PER_BH + ro + blk * 16;
  if (q == 0) aall[arow + m] = asum;

  // A-fragment for PV: lane (m,q<2) needs P[m][8q..8q+7] from lanes m+32q, m+32q+16
  unsigned int d0 = (unsigned int)pb0 | ((unsigned int)pb1 << 16);
  unsigned int d1 = (unsigned int)pb2 | ((unsigned int)pb3 << 16);
  const int s0l = m + 32 * (q & 1);
  unsigned int u0 = __shfl(d0, s0l, 64);
  unsigned int u1 = __shfl(d1, s0l, 64);
  unsigned int u2 = __shfl(d0, s0l + 16, 64);
  unsigned int u3 = __shfl(d1, s0l + 16, 64);
  union { uintx4 i; bf16x8 b; } pau;
  pau.i = (q < 2) ? (uintx4){u0, u1, u2, u3} : (uintx4){0u, 0u, 0u, 0u};
  const bf16x8 pa = pau.b;

  // Y = P . v, 4 column chunks of 16; K padded to 32 with zeros
#pragma unroll
  for (int c = 0; c < 4; c++) {
    union { uintx4 i; bf16x8 b; } bvu;
    bvu.i = (uintx4){0u, 0u, 0u, 0u};
    if (q < 2) bvu.b = *(const bf16x8*)&vtw[(c * 16 + m) * 24 + q * 8];
    floatx4 y = (floatx4){0.f, 0.f, 0.f, 0.f};
    y = __builtin_amdgcn_mfma_f32_16x16x32_bf16(pa, bvu.b, y, 0, 0, 0);
#pragma unroll
    for (int r = 0; r < 4; r++)
      yall[(arow + q * 4 + r) * 64 + c * 16 + m] = __float2bfloat16(y[r]);
  }
}

// ---- combine: U = sum_l y_l[i>>l] / (sum_l a_l[i>>l] + eps) ---------------
__global__ __launch_bounds__(256) void combine_kernel(
    const unsigned short* __restrict__ yall, const float* __restrict__ aall,
    __hip_bfloat16* __restrict__ Ub) {
  int idx = blockIdx.x * 256 + threadIdx.x;  // 32*4096*64
  int d = idx & 63;
  int i = (idx >> 6) & 4095;
  int bh = idx >> 18;
  size_t base = (size_t)bh * ROWS_PER_BH;
  float Y = 0.f, Aa = 0.f;
#pragma unroll
  for (int l = 0; l < 8; l++) {
    int r = (8192 - (8192 >> l)) + (i >> l);
    Y += bu2f(yall[(base + r) * 64 + d]);
    Aa += aall[base + r];
  }
  float u = Y / (Aa + 1e-8f);
  int b = bh >> 3, h = bh & 7;
  size_t m = (size_t)b * 4096 + i;
  Ub[m * 512 + (size_t)h * 64 + d] = __float2bfloat16(u);
}

// ---------------------------------------------------------------------------
extern "C" void kernel_launch(void* const* d_in, const int* in_sizes, int n_in,
                              void* d_out, int out_size, void* d_ws, size_t ws_size,
                              hipStream_t stream) {
  const float* x     = (const float*)d_in[0];  // [4,4096,1024]
  const float* w_qkv = (const float*)d_in[1];  // [1536,1024]
  const float* w_out = (const float*)d_in[2];  // [1024,512]
  const float* b_out = (const float*)d_in[3];  // [1024]
  float* out = (float*)d_out;

  char* ws = (char*)d_ws;
  __hip_bfloat16* xb    = (__hip_bfloat16*)(ws + 0);           // 33554432 B
  __hip_bfloat16* wqkvb = (__hip_bfloat16*)(ws + 33554432);    //  3145728 B
  __hip_bfloat16* wob   = (__hip_bfloat16*)(ws + 36700160);    //  1048576 B
  __hip_bfloat16* qp    = (__hip_bfloat16*)(ws + 37748736);    // 33423360 B
  __hip_bfloat16* kp    = (__hip_bfloat16*)(ws + 71172096);    // 33423360 B
  __hip_bfloat16* vp    = (__hip_bfloat16*)(ws + 104595456);   // 33423360 B
  __hip_bfloat16* yall  = (__hip_bfloat16*)(ws + 138018816);   // 33423360 B
  float* aall           = (float*)(ws + 171442176);            //  1044480 B
  __hip_bfloat16* Ub    = (__hip_bfloat16*)(ws + 172486656);   // 16777216 B

  // 1) converts
  f2b_kernel<<<16384, 256, 0, stream>>>(x, xb, 16777216);
  f2b_kernel<<<1536, 256, 0, stream>>>(w_qkv, wqkvb, 1572864);
  f2b_kernel<<<512, 256, 0, stream>>>(w_out, wob, 524288);

  // 2) qkv projection + scatter (256x256 tiles: 64 x 6 blocks, 512 thr)
  gemm_qkv_kernel<<<dim3(64, 6), 512, 0, stream>>>(
      (const unsigned short*)xb, (const unsigned short*)wqkvb, qp, kp, vp);

  // 3) pyramid levels 1..7, single launch
  pyramid_all_kernel<<<1024, 256, 0, stream>>>(qp, kp, vp);

  // 4) block attention over all levels (1 wave / block, 4 waves / wg)
  attn_kernel<<<dim3(128, 32), 256, 0, stream>>>(
      (const unsigned short*)qp, (const unsigned short*)kp,
      (const unsigned short*)vp, yall, aall);

  // 5) combine to U (bf16)
  combine_kernel<<<32768, 256, 0, stream>>>((const unsigned short*)yall, aall, Ub);

  // 6) out projection + bias (256x256 tiles: 64 x 4 blocks)
  gemm_out_kernel<<<dim3(64, 4), 512, 0, stream>>>(
      (const unsigned short*)Ub, (const unsigned short*)wob, b_out, out);
}

// Round 3
// 264.672 us; speedup vs baseline: 1.0791x; 1.0722x over previous
//
#include <hip/hip_runtime.h>
#include <hip/hip_bf16.h>

// ---------------------------------------------------------------------------
// HAttention1D: B=4 N=4096 DIM=1024 HEADS=8 DH=64 BSZ=16, 8 levels (0..7)
//  1) f2b3: x, w_qkv, w_out -> bf16 (single launch)
//  2) gemm_qkv (bf16 MFMA, 128x128, BK=64, XOR-swizzled LDS): qkv = x@w_qkv^T,
//     scatter epilogue (q*0.125) into (bh,row,d) pyramids
//  3) pyramid_all: per-(bh,128-row-chunk) WG computes levels 1..7 in LDS
//  4) attn: ONE WAVE per 16x16 block, MFMA S^T=k.q^T then PV; y stored bf16
//  5) combine (vectorized, 4 d/thread): U = sum_l y_l / (sum_l a_l + eps)
//  6) gemm_out (bf16 MFMA, 128x128): out = U @ w_out^T + b_out
// ---------------------------------------------------------------------------

typedef __bf16 bf16x8 __attribute__((ext_vector_type(8)));
typedef float floatx4 __attribute__((ext_vector_type(4)));
typedef unsigned short ushortx8 __attribute__((ext_vector_type(8)));
typedef unsigned int uintx4 __attribute__((ext_vector_type(4)));

#define ROWS_PER_BH 8160  // 4096+2048+1024+512+256+128+64+32

__device__ __forceinline__ void g2lds16(const void* g, void* l) {
  __builtin_amdgcn_global_load_lds(
      (const __attribute__((address_space(1))) void*)g,
      (__attribute__((address_space(3))) void*)l, 16, 0, 0);
}

__device__ __forceinline__ unsigned short f2bu(float x) {
  __hip_bfloat16 h = __float2bfloat16(x);
  return *(unsigned short*)&h;
}
__device__ __forceinline__ float bu2f(unsigned short u) {
  __hip_bfloat16 h = *(__hip_bfloat16*)&u;
  return __bfloat162float(h);
}

// ---- fp32 -> bf16 convert, all three tensors in one launch ----------------
// ranges (in elements): x 16777216 | w_qkv 1572864 | w_out 524288
__global__ __launch_bounds__(256) void f2b3_kernel(const float* __restrict__ x,
                                                   const float* __restrict__ wq,
                                                   const float* __restrict__ wo,
                                                   __hip_bfloat16* __restrict__ xb,
                                                   __hip_bfloat16* __restrict__ wqb,
                                                   __hip_bfloat16* __restrict__ wob) {
  int i0 = (blockIdx.x * 256 + threadIdx.x) * 4;
  const float* s;
  __hip_bfloat16* d;
  if (i0 < 16777216) {
    s = x; d = xb;
  } else if (i0 < 16777216 + 1572864) {
    s = wq + (i0 - 16777216); d = wqb + (i0 - 16777216); i0 = 0;
    // keep pointer math simple: s/d already offset, index from 0
    float4 v = *(const float4*)s;
    d[0] = __float2bfloat16(v.x); d[1] = __float2bfloat16(v.y);
    d[2] = __float2bfloat16(v.z); d[3] = __float2bfloat16(v.w);
    return;
  } else {
    s = wo + (i0 - 16777216 - 1572864); d = wob + (i0 - 16777216 - 1572864);
    float4 v = *(const float4*)s;
    d[0] = __float2bfloat16(v.x); d[1] = __float2bfloat16(v.y);
    d[2] = __float2bfloat16(v.z); d[3] = __float2bfloat16(v.w);
    return;
  }
  float4 v = *(const float4*)(s + i0);
  d[i0 + 0] = __float2bfloat16(v.x);
  d[i0 + 1] = __float2bfloat16(v.y);
  d[i0 + 2] = __float2bfloat16(v.z);
  d[i0 + 3] = __float2bfloat16(v.w);
}

// ---- shared GEMM core: 128x128 tile, BK=64, XOR-swizzled LDS --------------
// Staging: lane loads global chunk (lane&7)^(lane>>3) of its row, so LDS
// position p of row r holds chunk p^(r&7). Fragment ds_read_b128 at position
// (kk*4+quad)^(lane&7) -> every quad spans all 8 bank groups (2-way = free).
template <int K>
__device__ __forceinline__ void gemm_core(const unsigned short* __restrict__ A,
                                          const unsigned short* __restrict__ B,
                                          unsigned short* ldsA, unsigned short* ldsB,
                                          int tM, int tN, floatx4 acc[4][4]) {
  const int tid = threadIdx.x;
  const int lane = tid & 63, w = tid >> 6;
  const int wm = w >> 1, wn = w & 1;
  const int lr = lane >> 3;            // row-within-8 for staging
  const int gch = (lane & 7) ^ lr;     // XOR-swizzled global chunk
  const unsigned short* Ag = A + (size_t)(tM + w * 32 + lr) * K + gch * 8;
  const unsigned short* Bg = B + (size_t)(tN + w * 32 + lr) * K + gch * 8;
  unsigned short* lA = &ldsA[w * 2048 + lane * 8];
  unsigned short* lB = &ldsB[w * 2048 + lane * 8];

  const int rA = wm * 64 + (lane & 15);
  const int rB = wn * 64 + (lane & 15);
  const int quad = lane >> 4;
  const int sw = lane & 7;             // fragment row & 7

  for (int kt = 0; kt < K; kt += 64) {
    __syncthreads();
#pragma unroll
    for (int c = 0; c < 4; c++) {
      g2lds16(Ag + (size_t)(c * 8) * K + kt, lA + c * 512);
      g2lds16(Bg + (size_t)(c * 8) * K + kt, lB + c * 512);
    }
    __syncthreads();
#pragma unroll
    for (int kk = 0; kk < 2; kk++) {
      bf16x8 af[4], bv[4];
#pragma unroll
      for (int i = 0; i < 4; i++)
        af[i] = *(const bf16x8*)&ldsA[(rA + i * 16) * 64 + (((kk * 4 + quad) ^ sw) * 8)];
#pragma unroll
      for (int j = 0; j < 4; j++)
        bv[j] = *(const bf16x8*)&ldsB[(rB + j * 16) * 64 + (((kk * 4 + quad) ^ sw) * 8)];
#pragma unroll
      for (int i = 0; i < 4; i++)
#pragma unroll
        for (int j = 0; j < 4; j++)
          acc[i][j] = __builtin_amdgcn_mfma_f32_16x16x32_bf16(af[i], bv[j], acc[i][j], 0, 0, 0);
    }
  }
}

// ---- GEMM1: qkv = x[16384,1024] @ w_qkv[1536,1024]^T, scatter epilogue ----
__global__ __launch_bounds__(256) void gemm_qkv_kernel(
    const unsigned short* __restrict__ A,   // xb [16384,1024] bf16
    const unsigned short* __restrict__ B,   // wqkvb [1536,1024] bf16
    __hip_bfloat16* __restrict__ qp, __hip_bfloat16* __restrict__ kp,
    __hip_bfloat16* __restrict__ vp) {
  __shared__ unsigned short ldsA[128 * 64];
  __shared__ unsigned short ldsB[128 * 64];
  const int lane = threadIdx.x & 63, w = threadIdx.x >> 6;
  const int wm = w >> 1, wn = w & 1;
  const int tM = blockIdx.x * 128, tN = blockIdx.y * 128;

  floatx4 acc[4][4];
#pragma unroll
  for (int i = 0; i < 4; i++)
#pragma unroll
    for (int j = 0; j < 4; j++) acc[i][j] = (floatx4){0.f, 0.f, 0.f, 0.f};

  gemm_core<1024>(A, B, ldsA, ldsB, tM, tN, acc);

  // epilogue: C/D layout col=lane&15, row=(lane>>4)*4+r  [verified m89]
  const int quad = lane >> 4;
#pragma unroll
  for (int i = 0; i < 4; i++) {
#pragma unroll
    for (int j = 0; j < 4; j++) {
      const int c = tN + wn * 64 + j * 16 + (lane & 15);
      const int tensor = c >> 9;         // 0=q 1=k 2=v
      const int rem = c & 511;
      const int h = rem >> 6, d = rem & 63;
      __hip_bfloat16* dstbuf = (tensor == 0) ? qp : ((tensor == 1) ? kp : vp);
      const float scale = (tensor == 0) ? 0.125f : 1.0f;  // DH^-0.5
#pragma unroll
      for (int r = 0; r < 4; r++) {
        const int m = tM + wm * 64 + i * 16 + quad * 4 + r;
        const int b = m >> 12, n = m & 4095;
        size_t dst = ((size_t)(b * 8 + h) * ROWS_PER_BH + n) * 64 + d;
        dstbuf[dst] = __float2bfloat16(acc[i][j][r] * scale);
      }
    }
  }
}

// ---- GEMM2: out = U[16384,512] @ w_out[1024,512]^T + b_out ----------------
__global__ __launch_bounds__(256) void gemm_out_kernel(
    const unsigned short* __restrict__ A,   // Ub [16384,512] bf16
    const unsigned short* __restrict__ B,   // wob [1024,512] bf16
    const float* __restrict__ bias, float* __restrict__ out) {
  __shared__ unsigned short ldsA[128 * 64];
  __shared__ unsigned short ldsB[128 * 64];
  const int lane = threadIdx.x & 63, w = threadIdx.x >> 6;
  const int wm = w >> 1, wn = w & 1;
  const int tM = blockIdx.x * 128, tN = blockIdx.y * 128;

  floatx4 acc[4][4];
#pragma unroll
  for (int i = 0; i < 4; i++)
#pragma unroll
    for (int j = 0; j < 4; j++) acc[i][j] = (floatx4){0.f, 0.f, 0.f, 0.f};

  gemm_core<512>(A, B, ldsA, ldsB, tM, tN, acc);

  const int quad = lane >> 4;
#pragma unroll
  for (int i = 0; i < 4; i++) {
#pragma unroll
    for (int j = 0; j < 4; j++) {
      const int c = tN + wn * 64 + j * 16 + (lane & 15);
      const float bb = bias[c];
#pragma unroll
      for (int r = 0; r < 4; r++) {
        const int m = tM + wm * 64 + i * 16 + quad * 4 + r;
        out[(size_t)m * 1024 + c] = acc[i][j][r] + bb;
      }
    }
  }
}

// ---- pyramid, single kernel: WG = (bh, 128-row chunk), levels 1..7 --------
__global__ __launch_bounds__(256) void pyramid_all_kernel(
    __hip_bfloat16* __restrict__ qp, __hip_bfloat16* __restrict__ kp,
    __hip_bfloat16* __restrict__ vp) {
  __shared__ unsigned short qs[128 * 64], ks[128 * 64], vs[128 * 64];  // 48 KB
  const int bh = blockIdx.x >> 5;
  const int chunk = blockIdx.x & 31;
  const int tid = threadIdx.x;
  const size_t base = (size_t)bh * ROWS_PER_BH;
  const size_t g0 = (base + chunk * 128) * 64;
  const unsigned short* qg = (const unsigned short*)qp;
  const unsigned short* kg = (const unsigned short*)kp;
  const unsigned short* vg = (const unsigned short*)vp;
#pragma unroll
  for (int c = 0; c < 4; c++) {
    int off = c * 2048 + tid * 8;
    *(ushortx8*)&qs[off] = *(const ushortx8*)(qg + g0 + off);
    *(ushortx8*)&ks[off] = *(const ushortx8*)(kg + g0 + off);
    *(ushortx8*)&vs[off] = *(const ushortx8*)(vg + g0 + off);
  }
  const int offs[8] = {0, 4096, 6144, 7168, 7680, 7936, 8064, 8128};
#pragma unroll
  for (int l = 1; l <= 7; l++) {
    __syncthreads();
    const int nOut = 128 >> l;
    for (int e = tid; e < nOut * 32; e += 256) {
      const int i = e >> 5, dp = (e & 31) * 2;
      const int a = (i << l) * 64 + dp;
      const int b = a + (1 << (l - 1)) * 64;
      unsigned short q0 = f2bu(0.5f * (bu2f(qs[a]) + bu2f(qs[b])));
      unsigned short q1 = f2bu(0.5f * (bu2f(qs[a + 1]) + bu2f(qs[b + 1])));
      unsigned short k0 = f2bu(0.5f * (bu2f(ks[a]) + bu2f(ks[b])));
      unsigned short k1 = f2bu(0.5f * (bu2f(ks[a + 1]) + bu2f(ks[b + 1])));
      unsigned short v0 = f2bu(bu2f(vs[a]) + bu2f(vs[b]));
      unsigned short v1 = f2bu(bu2f(vs[a + 1]) + bu2f(vs[b + 1]));
      qs[a] = q0; qs[a + 1] = q1;
      ks[a] = k0; ks[a + 1] = k1;
      vs[a] = v0; vs[a + 1] = v1;
      const size_t grow = (base + offs[l] + (size_t)chunk * nOut + i) * 64 + dp;
      *(unsigned int*)((unsigned short*)qp + grow) = (unsigned int)q0 | ((unsigned int)q1 << 16);
      *(unsigned int*)((unsigned short*)kp + grow) = (unsigned int)k0 | ((unsigned int)k1 << 16);
      *(unsigned int*)((unsigned short*)vp + grow) = (unsigned int)v0 | ((unsigned int)v1 << 16);
    }
  }
}

// ---- block attention: ONE WAVE per (level-block, bh), MFMA, no barriers ---
__global__ __launch_bounds__(256) void attn_kernel(
    const unsigned short* __restrict__ qp, const unsigned short* __restrict__ kp,
    const unsigned short* __restrict__ vp, __hip_bfloat16* __restrict__ yall,
    float* __restrict__ aall) {
  __shared__ __align__(16) unsigned short vT[4][64 * 24];  // per-wave slice, stride 24
  const int w = threadIdx.x >> 6, lane = threadIdx.x & 63;
  const int g = blockIdx.x * 4 + w;
  if (g >= 510) return;
  const int bh = blockIdx.y;
  int level, blk;
  if (g < 256)      { level = 0; blk = g; }
  else if (g < 384) { level = 1; blk = g - 256; }
  else if (g < 448) { level = 2; blk = g - 384; }
  else if (g < 480) { level = 3; blk = g - 448; }
  else if (g < 496) { level = 4; blk = g - 480; }
  else if (g < 504) { level = 5; blk = g - 496; }
  else if (g < 508) { level = 6; blk = g - 504; }
  else              { level = 7; blk = g - 508; }
  const int ro = 8192 - (8192 >> level);
  const int kblk = (level == 0) ? blk : (blk ^ 1);  // sibling key flip (v NOT flipped)
  const int m = lane & 15, q = lane >> 4;
  const size_t qbase = ((size_t)bh * ROWS_PER_BH + ro + blk * 16) * 64;
  const size_t kbase = ((size_t)bh * ROWS_PER_BH + ro + kblk * 16) * 64;

  // fragment loads: A-op = k rows, B-op = q rows (both contiguous 8 bf16)
  const bf16x8 ka0 = *(const bf16x8*)(kp + kbase + m * 64 + q * 8);
  const bf16x8 ka1 = *(const bf16x8*)(kp + kbase + m * 64 + 32 + q * 8);
  const bf16x8 qb0 = *(const bf16x8*)(qp + qbase + m * 64 + q * 8);
  const bf16x8 qb1 = *(const bf16x8*)(qp + qbase + m * 64 + 32 + q * 8);

  // stage v transposed into LDS: vT[d][vrow], row stride 24
  const ushortx8 v0 = *(const ushortx8*)(vp + qbase + m * 64 + q * 16);
  const ushortx8 v1 = *(const ushortx8*)(vp + qbase + m * 64 + q * 16 + 8);
  unsigned short* vtw = vT[w];
#pragma unroll
  for (int j = 0; j < 8; j++) vtw[(q * 16 + j) * 24 + m] = v0[j];
#pragma unroll
  for (int j = 0; j < 8; j++) vtw[(q * 16 + 8 + j) * 24 + m] = v1[j];

  // S^T: D[j=quad*4+r][i=lane&15] = sum_d k[j][d] q[i][d]
  floatx4 s = (floatx4){0.f, 0.f, 0.f, 0.f};
  s = __builtin_amdgcn_mfma_f32_16x16x32_bf16(ka0, qb0, s, 0, 0, 0);
  s = __builtin_amdgcn_mfma_f32_16x16x32_bf16(ka1, qb1, s, 0, 0, 0);

  // P = exp(S) in bf16 (numerator & denominator use the SAME rounded values)
  unsigned short pb0 = f2bu(__expf(s[0])), pb1 = f2bu(__expf(s[1]));
  unsigned short pb2 = f2bu(__expf(s[2])), pb3 = f2bu(__expf(s[3]));
  float asum = bu2f(pb0) + bu2f(pb1) + bu2f(pb2) + bu2f(pb3);
  asum += __shfl_xor(asum, 16, 64);
  asum += __shfl_xor(asum, 32, 64);
  const size_t arow = (size_t)bh * ROWS_PER_BH + ro + blk * 16;
  if (q == 0) aall[arow + m] = asum;

  // A-fragment for PV: lane (m,q<2) needs P[m][8q..8q+7] from lanes m+32q, m+32q+16
  unsigned int d0 = (unsigned int)pb0 | ((unsigned int)pb1 << 16);
  unsigned int d1 = (unsigned int)pb2 | ((unsigned int)pb3 << 16);
  const int s0l = m + 32 * (q & 1);
  unsigned int u0 = __shfl(d0, s0l, 64);
  unsigned int u1 = __shfl(d1, s0l, 64);
  unsigned int u2 = __shfl(d0, s0l + 16, 64);
  unsigned int u3 = __shfl(d1, s0l + 16, 64);
  union { uintx4 i; bf16x8 b; } pau;
  pau.i = (q < 2) ? (uintx4){u0, u1, u2, u3} : (uintx4){0u, 0u, 0u, 0u};
  const bf16x8 pa = pau.b;

  // Y = P . v, 4 column chunks of 16; K padded to 32 with zeros
#pragma unroll
  for (int c = 0; c < 4; c++) {
    union { uintx4 i; bf16x8 b; } bvu;
    bvu.i = (uintx4){0u, 0u, 0u, 0u};
    if (q < 2) bvu.b = *(const bf16x8*)&vtw[(c * 16 + m) * 24 + q * 8];
    floatx4 y = (floatx4){0.f, 0.f, 0.f, 0.f};
    y = __builtin_amdgcn_mfma_f32_16x16x32_bf16(pa, bvu.b, y, 0, 0, 0);
#pragma unroll
    for (int r = 0; r < 4; r++)
      yall[(arow + q * 4 + r) * 64 + c * 16 + m] = __float2bfloat16(y[r]);
  }
}

// ---- combine (vectorized): U = sum_l y_l[i>>l] / (sum_l a_l[i>>l] + eps) --
// 4 d-elements per thread: 8B loads per level, 8B store.
__global__ __launch_bounds__(256) void combine_kernel(
    const unsigned short* __restrict__ yall, const float* __restrict__ aall,
    __hip_bfloat16* __restrict__ Ub) {
  int idx = blockIdx.x * 256 + threadIdx.x;  // 32 bh * 4096 i * 16 dquads
  int d4 = (idx & 15) * 4;
  int i = (idx >> 4) & 4095;
  int bh = idx >> 16;
  size_t base = (size_t)bh * ROWS_PER_BH;
  float Y0 = 0.f, Y1 = 0.f, Y2 = 0.f, Y3 = 0.f, Aa = 0.f;
#pragma unroll
  for (int l = 0; l < 8; l++) {
    int r = (8192 - (8192 >> l)) + (i >> l);
    uint2 yv = *(const uint2*)(yall + (base + r) * 64 + d4);
    Y0 += bu2f((unsigned short)(yv.x & 0xffff));
    Y1 += bu2f((unsigned short)(yv.x >> 16));
    Y2 += bu2f((unsigned short)(yv.y & 0xffff));
    Y3 += bu2f((unsigned short)(yv.y >> 16));
    Aa += aall[base + r];
  }
  float inv = 1.0f / (Aa + 1e-8f);
  unsigned int o0 = (unsigned int)f2bu(Y0 * inv) | ((unsigned int)f2bu(Y1 * inv) << 16);
  unsigned int o1 = (unsigned int)f2bu(Y2 * inv) | ((unsigned int)f2bu(Y3 * inv) << 16);
  int b = bh >> 3, h = bh & 7;
  size_t m = (size_t)b * 4096 + i;
  uint2 o = {o0, o1};
  *(uint2*)((unsigned short*)Ub + m * 512 + (size_t)h * 64 + d4) = o;
}

// ---------------------------------------------------------------------------
extern "C" void kernel_launch(void* const* d_in, const int* in_sizes, int n_in,
                              void* d_out, int out_size, void* d_ws, size_t ws_size,
                              hipStream_t stream) {
  const float* x     = (const float*)d_in[0];  // [4,4096,1024]
  const float* w_qkv = (const float*)d_in[1];  // [1536,1024]
  const float* w_out = (const float*)d_in[2];  // [1024,512]
  const float* b_out = (const float*)d_in[3];  // [1024]
  float* out = (float*)d_out;

  char* ws = (char*)d_ws;
  __hip_bfloat16* xb    = (__hip_bfloat16*)(ws + 0);           // 33554432 B
  __hip_bfloat16* wqkvb = (__hip_bfloat16*)(ws + 33554432);    //  3145728 B
  __hip_bfloat16* wob   = (__hip_bfloat16*)(ws + 36700160);    //  1048576 B
  __hip_bfloat16* qp    = (__hip_bfloat16*)(ws + 37748736);    // 33423360 B
  __hip_bfloat16* kp    = (__hip_bfloat16*)(ws + 71172096);    // 33423360 B
  __hip_bfloat16* vp    = (__hip_bfloat16*)(ws + 104595456);   // 33423360 B
  __hip_bfloat16* yall  = (__hip_bfloat16*)(ws + 138018816);   // 33423360 B
  float* aall           = (float*)(ws + 171442176);            //  1044480 B
  __hip_bfloat16* Ub    = (__hip_bfloat16*)(ws + 172486656);   // 16777216 B

  // 1) converts (single launch): (16777216+1572864+524288)/4/256 = 18432
  f2b3_kernel<<<18432, 256, 0, stream>>>(x, w_qkv, w_out, xb, wqkvb, wob);

  // 2) qkv projection + scatter
  gemm_qkv_kernel<<<dim3(128, 12), 256, 0, stream>>>(
      (const unsigned short*)xb, (const unsigned short*)wqkvb, qp, kp, vp);

  // 3) pyramid levels 1..7, single launch
  pyramid_all_kernel<<<1024, 256, 0, stream>>>(qp, kp, vp);

  // 4) block attention over all levels (1 wave / block, 4 waves / wg)
  attn_kernel<<<dim3(128, 32), 256, 0, stream>>>(
      (const unsigned short*)qp, (const unsigned short*)kp,
      (const unsigned short*)vp, yall, aall);

  // 5) combine to U (bf16), 4 d/thread
  combine_kernel<<<8192, 256, 0, stream>>>((const unsigned short*)yall, aall, Ub);

  // 6) out projection + bias
  gemm_out_kernel<<<dim3(128, 8), 256, 0, stream>>>(
      (const unsigned short*)Ub, (const unsigned short*)wob, b_out, out);
}

// Round 5
// 262.890 us; speedup vs baseline: 1.0864x; 1.0068x over previous
//
#include <hip/hip_runtime.h>
#include <hip/hip_bf16.h>

// ---------------------------------------------------------------------------
// HAttention1D: B=4 N=4096 DIM=1024 HEADS=8 DH=64 BSZ=16, 8 levels (0..7)
//  1) f2b3: x, w_qkv, w_out -> bf16 (single launch)
//  2) gemm_qkv (128x128 MFMA): qkv = x@w_qkv^T; epilogue scatters level-0
//     AND emits level-4 rows directly from f32 accumulators (cross-quad sum)
//  3) pyramid47: per-bh, levels 5..7 from level-4 in LDS
//  4) attn47: one wave per coarse block (levels 4..7), writes yall/aall
//  5) fused03: per (bh, 256-row chunk): stage level-0 qkv to swizzled LDS,
//     then INTERLEAVED attn-l / build-(l+1) (in-place pyramid destroys half
//     of level l, so attn-l must run first): attn0(y0 in regs) -> pyr1 ->
//     attn1 -> pyr2 -> attn2 -> pyr3 -> attn3 -> fused final combine -> Ub
//  6) gemm_out (128x128 MFMA): out = U @ w_out^T + b_out
// ---------------------------------------------------------------------------

typedef __bf16 bf16x8 __attribute__((ext_vector_type(8)));
typedef float floatx4 __attribute__((ext_vector_type(4)));
typedef unsigned short ushortx8 __attribute__((ext_vector_type(8)));
typedef unsigned int uintx4 __attribute__((ext_vector_type(4)));

#define ROWS_PER_BH 8160  // 4096+2048+1024+512+256+128+64+32

__device__ __forceinline__ void g2lds16(const void* g, void* l) {
  __builtin_amdgcn_global_load_lds(
      (const __attribute__((address_space(1))) void*)g,
      (__attribute__((address_space(3))) void*)l, 16, 0, 0);
}

__device__ __forceinline__ unsigned short f2bu(float x) {
  __hip_bfloat16 h = __float2bfloat16(x);
  return *(unsigned short*)&h;
}
__device__ __forceinline__ float bu2f(unsigned short u) {
  __hip_bfloat16 h = *(__hip_bfloat16*)&u;
  return __bfloat162float(h);
}

// ---- fp32 -> bf16 convert, all three tensors in one launch ----------------
__global__ __launch_bounds__(256) void f2b3_kernel(const float* __restrict__ x,
                                                   const float* __restrict__ wq,
                                                   const float* __restrict__ wo,
                                                   __hip_bfloat16* __restrict__ xb,
                                                   __hip_bfloat16* __restrict__ wqb,
                                                   __hip_bfloat16* __restrict__ wob) {
  int i0 = (blockIdx.x * 256 + threadIdx.x) * 4;
  const float* s;
  __hip_bfloat16* d;
  if (i0 < 16777216) {
    s = x; d = xb;
  } else if (i0 < 16777216 + 1572864) {
    s = wq + (i0 - 16777216); d = wqb + (i0 - 16777216);
    float4 v = *(const float4*)s;
    d[0] = __float2bfloat16(v.x); d[1] = __float2bfloat16(v.y);
    d[2] = __float2bfloat16(v.z); d[3] = __float2bfloat16(v.w);
    return;
  } else {
    s = wo + (i0 - 16777216 - 1572864); d = wob + (i0 - 16777216 - 1572864);
    float4 v = *(const float4*)s;
    d[0] = __float2bfloat16(v.x); d[1] = __float2bfloat16(v.y);
    d[2] = __float2bfloat16(v.z); d[3] = __float2bfloat16(v.w);
    return;
  }
  float4 v = *(const float4*)(s + i0);
  d[i0 + 0] = __float2bfloat16(v.x);
  d[i0 + 1] = __float2bfloat16(v.y);
  d[i0 + 2] = __float2bfloat16(v.z);
  d[i0 + 3] = __float2bfloat16(v.w);
}

// ---- shared GEMM core: 128x128 tile, BK=64, XOR-swizzled LDS --------------
template <int K>
__device__ __forceinline__ void gemm_core(const unsigned short* __restrict__ A,
                                          const unsigned short* __restrict__ B,
                                          unsigned short* ldsA, unsigned short* ldsB,
                                          int tM, int tN, floatx4 acc[4][4]) {
  const int tid = threadIdx.x;
  const int lane = tid & 63, w = tid >> 6;
  const int wm = w >> 1, wn = w & 1;
  const int lr = lane >> 3;            // row-within-8 for staging
  const int gch = (lane & 7) ^ lr;     // XOR-swizzled global chunk
  const unsigned short* Ag = A + (size_t)(tM + w * 32 + lr) * K + gch * 8;
  const unsigned short* Bg = B + (size_t)(tN + w * 32 + lr) * K + gch * 8;
  unsigned short* lA = &ldsA[w * 2048 + lane * 8];
  unsigned short* lB = &ldsB[w * 2048 + lane * 8];

  const int rA = wm * 64 + (lane & 15);
  const int rB = wn * 64 + (lane & 15);
  const int quad = lane >> 4;
  const int sw = lane & 7;             // fragment row & 7

  for (int kt = 0; kt < K; kt += 64) {
    __syncthreads();
#pragma unroll
    for (int c = 0; c < 4; c++) {
      g2lds16(Ag + (size_t)(c * 8) * K + kt, lA + c * 512);
      g2lds16(Bg + (size_t)(c * 8) * K + kt, lB + c * 512);
    }
    __syncthreads();
#pragma unroll
    for (int kk = 0; kk < 2; kk++) {
      bf16x8 af[4], bv[4];
#pragma unroll
      for (int i = 0; i < 4; i++)
        af[i] = *(const bf16x8*)&ldsA[(rA + i * 16) * 64 + (((kk * 4 + quad) ^ sw) * 8)];
#pragma unroll
      for (int j = 0; j < 4; j++)
        bv[j] = *(const bf16x8*)&ldsB[(rB + j * 16) * 64 + (((kk * 4 + quad) ^ sw) * 8)];
#pragma unroll
      for (int i = 0; i < 4; i++)
#pragma unroll
        for (int j = 0; j < 4; j++)
          acc[i][j] = __builtin_amdgcn_mfma_f32_16x16x32_bf16(af[i], bv[j], acc[i][j], 0, 0, 0);
    }
  }
}

// ---- GEMM1: qkv = x[16384,1024] @ w_qkv[1536,1024]^T ----------------------
// epilogue: scatter level-0 + emit level-4 rows (mean/mean/sum of 16 rows)
__global__ __launch_bounds__(256) void gemm_qkv_kernel(
    const unsigned short* __restrict__ A,   // xb [16384,1024] bf16
    const unsigned short* __restrict__ B,   // wqkvb [1536,1024] bf16
    __hip_bfloat16* __restrict__ qp, __hip_bfloat16* __restrict__ kp,
    __hip_bfloat16* __restrict__ vp) {
  __shared__ unsigned short ldsA[128 * 64];
  __shared__ unsigned short ldsB[128 * 64];
  const int lane = threadIdx.x & 63, w = threadIdx.x >> 6;
  const int wm = w >> 1, wn = w & 1;
  const int tM = blockIdx.x * 128, tN = blockIdx.y * 128;

  floatx4 acc[4][4];
#pragma unroll
  for (int i = 0; i < 4; i++)
#pragma unroll
    for (int j = 0; j < 4; j++) acc[i][j] = (floatx4){0.f, 0.f, 0.f, 0.f};

  gemm_core<1024>(A, B, ldsA, ldsB, tM, tN, acc);

  // epilogue: C/D layout col=lane&15, row=(lane>>4)*4+r  [verified m89]
  const int quad = lane >> 4, m15 = lane & 15;
#pragma unroll
  for (int i = 0; i < 4; i++) {
#pragma unroll
    for (int j = 0; j < 4; j++) {
      const int c = tN + wn * 64 + j * 16 + m15;
      const int tensor = c >> 9;         // 0=q 1=k 2=v
      const int rem = c & 511;
      const int h = rem >> 6, d = rem & 63;
      __hip_bfloat16* dstbuf = (tensor == 0) ? qp : ((tensor == 1) ? kp : vp);
      const float scale = (tensor == 0) ? 0.125f : 1.0f;  // DH^-0.5
#pragma unroll
      for (int r = 0; r < 4; r++) {
        const int m = tM + wm * 64 + i * 16 + quad * 4 + r;
        const int b = m >> 12, n = m & 4095;
        size_t dst = ((size_t)(b * 8 + h) * ROWS_PER_BH + n) * 64 + d;
        dstbuf[dst] = __float2bfloat16(acc[i][j][r] * scale);
      }
      // level-4 row: sum of 16 consecutive rows (in-lane 4 + cross-quad)
      float s4 = acc[i][j][0] + acc[i][j][1] + acc[i][j][2] + acc[i][j][3];
      s4 += __shfl_xor(s4, 16, 64);
      s4 += __shfl_xor(s4, 32, 64);
      if (quad == 0) {
        const int mrow = tM + wm * 64 + i * 16;     // multiple of 16
        const int b = mrow >> 12, n4 = (mrow & 4095) >> 4;
        // q: mean*0.125; k: mean; v: sum
        const float val = (tensor == 0) ? s4 * (0.125f / 16.f)
                         : ((tensor == 1) ? s4 * (1.f / 16.f) : s4);
        dstbuf[((size_t)(b * 8 + h) * ROWS_PER_BH + 7680 + n4) * 64 + d] =
            __float2bfloat16(val);
      }
    }
  }
}

// ---- GEMM2: out = U[16384,512] @ w_out[1024,512]^T + b_out ----------------
__global__ __launch_bounds__(256) void gemm_out_kernel(
    const unsigned short* __restrict__ A,   // Ub [16384,512] bf16
    const unsigned short* __restrict__ B,   // wob [1024,512] bf16
    const float* __restrict__ bias, float* __restrict__ out) {
  __shared__ unsigned short ldsA[128 * 64];
  __shared__ unsigned short ldsB[128 * 64];
  const int lane = threadIdx.x & 63, w = threadIdx.x >> 6;
  const int wm = w >> 1, wn = w & 1;
  const int tM = blockIdx.x * 128, tN = blockIdx.y * 128;

  floatx4 acc[4][4];
#pragma unroll
  for (int i = 0; i < 4; i++)
#pragma unroll
    for (int j = 0; j < 4; j++) acc[i][j] = (floatx4){0.f, 0.f, 0.f, 0.f};

  gemm_core<512>(A, B, ldsA, ldsB, tM, tN, acc);

  const int quad = lane >> 4;
#pragma unroll
  for (int i = 0; i < 4; i++) {
#pragma unroll
    for (int j = 0; j < 4; j++) {
      const int c = tN + wn * 64 + j * 16 + (lane & 15);
      const float bb = bias[c];
#pragma unroll
      for (int r = 0; r < 4; r++) {
        const int m = tM + wm * 64 + i * 16 + quad * 4 + r;
        out[(size_t)m * 1024 + c] = acc[i][j][r] + bb;
      }
    }
  }
}

// ---- pyramid47: per bh, levels 5..7 from level-4 (plain LDS) --------------
__global__ __launch_bounds__(256) void pyramid47_kernel(
    __hip_bfloat16* __restrict__ qp, __hip_bfloat16* __restrict__ kp,
    __hip_bfloat16* __restrict__ vp) {
  __shared__ unsigned short qs[256 * 64], ks[256 * 64], vs[256 * 64];  // 96 KB
  const int bh = blockIdx.x;
  const int tid = threadIdx.x;
  const size_t base = (size_t)bh * ROWS_PER_BH;
  const size_t g0 = (base + 7680) * 64;
  const unsigned short* qg = (const unsigned short*)qp;
  const unsigned short* kg = (const unsigned short*)kp;
  const unsigned short* vg = (const unsigned short*)vp;
#pragma unroll
  for (int c = 0; c < 8; c++) {
    int off = c * 2048 + tid * 8;
    *(ushortx8*)&qs[off] = *(const ushortx8*)(qg + g0 + off);
    *(ushortx8*)&ks[off] = *(const ushortx8*)(kg + g0 + off);
    *(ushortx8*)&vs[off] = *(const ushortx8*)(vg + g0 + off);
  }
  const int offs[4] = {0, 7936, 8064, 8128};  // local levels 1..3 = global 5..7
#pragma unroll
  for (int l = 1; l <= 3; l++) {
    __syncthreads();
    const int nOut = 256 >> l;   // 128, 64, 32
    for (int e = tid; e < nOut * 32; e += 256) {
      const int i = e >> 5, dp = (e & 31) * 2;
      const int a = (i << l) * 64 + dp;
      const int b = a + (1 << (l - 1)) * 64;
      unsigned short q0 = f2bu(0.5f * (bu2f(qs[a]) + bu2f(qs[b])));
      unsigned short q1 = f2bu(0.5f * (bu2f(qs[a + 1]) + bu2f(qs[b + 1])));
      unsigned short k0 = f2bu(0.5f * (bu2f(ks[a]) + bu2f(ks[b])));
      unsigned short k1 = f2bu(0.5f * (bu2f(ks[a + 1]) + bu2f(ks[b + 1])));
      unsigned short v0 = f2bu(bu2f(vs[a]) + bu2f(vs[b]));
      unsigned short v1 = f2bu(bu2f(vs[a + 1]) + bu2f(vs[b + 1]));
      qs[a] = q0; qs[a + 1] = q1;
      ks[a] = k0; ks[a + 1] = k1;
      vs[a] = v0; vs[a + 1] = v1;
      const size_t grow = (base + offs[l] + i) * 64 + dp;
      *(unsigned int*)((unsigned short*)qp + grow) = (unsigned int)q0 | ((unsigned int)q1 << 16);
      *(unsigned int*)((unsigned short*)kp + grow) = (unsigned int)k0 | ((unsigned int)k1 << 16);
      *(unsigned int*)((unsigned short*)vp + grow) = (unsigned int)v0 | ((unsigned int)v1 << 16);
    }
  }
}

// ---- attn47: ONE WAVE per coarse block (levels 4..7) ----------------------
__global__ __launch_bounds__(256) void attn47_kernel(
    const unsigned short* __restrict__ qp, const unsigned short* __restrict__ kp,
    const unsigned short* __restrict__ vp, __hip_bfloat16* __restrict__ yall,
    float* __restrict__ aall) {
  __shared__ __align__(16) unsigned short vT[4][64 * 24];
  const int w = threadIdx.x >> 6, lane = threadIdx.x & 63;
  const int g = blockIdx.x * 4 + w;   // 0..31
  if (g >= 30) return;
  const int bh = blockIdx.y;
  int level, blk;
  if (g < 16)      { level = 4; blk = g; }
  else if (g < 24) { level = 5; blk = g - 16; }
  else if (g < 28) { level = 6; blk = g - 24; }
  else             { level = 7; blk = g - 28; }
  const int ro = 8192 - (8192 >> level);
  const int kblk = blk ^ 1;  // sibling key flip (v NOT flipped)
  const int m = lane & 15, q = lane >> 4;
  const size_t qbase = ((size_t)bh * ROWS_PER_BH + ro + blk * 16) * 64;
  const size_t kbase = ((size_t)bh * ROWS_PER_BH + ro + kblk * 16) * 64;

  const bf16x8 ka0 = *(const bf16x8*)(kp + kbase + m * 64 + q * 8);
  const bf16x8 ka1 = *(const bf16x8*)(kp + kbase + m * 64 + 32 + q * 8);
  const bf16x8 qb0 = *(const bf16x8*)(qp + qbase + m * 64 + q * 8);
  const bf16x8 qb1 = *(const bf16x8*)(qp + qbase + m * 64 + 32 + q * 8);

  const ushortx8 v0 = *(const ushortx8*)(vp + qbase + m * 64 + q * 16);
  const ushortx8 v1 = *(const ushortx8*)(vp + qbase + m * 64 + q * 16 + 8);
  unsigned short* vtw = vT[w];
#pragma unroll
  for (int j = 0; j < 8; j++) vtw[(q * 16 + j) * 24 + m] = v0[j];
#pragma unroll
  for (int j = 0; j < 8; j++) vtw[(q * 16 + 8 + j) * 24 + m] = v1[j];

  floatx4 s = (floatx4){0.f, 0.f, 0.f, 0.f};
  s = __builtin_amdgcn_mfma_f32_16x16x32_bf16(ka0, qb0, s, 0, 0, 0);
  s = __builtin_amdgcn_mfma_f32_16x16x32_bf16(ka1, qb1, s, 0, 0, 0);

  unsigned short pb0 = f2bu(__expf(s[0])), pb1 = f2bu(__expf(s[1]));
  unsigned short pb2 = f2bu(__expf(s[2])), pb3 = f2bu(__expf(s[3]));
  float asum = bu2f(pb0) + bu2f(pb1) + bu2f(pb2) + bu2f(pb3);
  asum += __shfl_xor(asum, 16, 64);
  asum += __shfl_xor(asum, 32, 64);
  const size_t arow = (size_t)bh * ROWS_PER_BH + ro + blk * 16;
  if (q == 0) aall[arow + m] = asum;

  unsigned int d0 = (unsigned int)pb0 | ((unsigned int)pb1 << 16);
  unsigned int d1 = (unsigned int)pb2 | ((unsigned int)pb3 << 16);
  const int s0l = m + 32 * (q & 1);
  unsigned int u0 = __shfl(d0, s0l, 64);
  unsigned int u1 = __shfl(d1, s0l, 64);
  unsigned int u2 = __shfl(d0, s0l + 16, 64);
  unsigned int u3 = __shfl(d1, s0l + 16, 64);
  union { uintx4 i; bf16x8 b; } pau;
  pau.i = (q < 2) ? (uintx4){u0, u1, u2, u3} : (uintx4){0u, 0u, 0u, 0u};
  const bf16x8 pa = pau.b;

#pragma unroll
  for (int c = 0; c < 4; c++) {
    union { uintx4 i; bf16x8 b; } bvu;
    bvu.i = (uintx4){0u, 0u, 0u, 0u};
    if (q < 2) bvu.b = *(const bf16x8*)&vtw[(c * 16 + m) * 24 + q * 8];
    floatx4 y = (floatx4){0.f, 0.f, 0.f, 0.f};
    y = __builtin_amdgcn_mfma_f32_16x16x32_bf16(pa, bvu.b, y, 0, 0, 0);
#pragma unroll
    for (int r = 0; r < 4; r++)
      yall[(arow + q * 4 + r) * 64 + c * 16 + m] = __float2bfloat16(y[r]);
  }
}

// ---- fused03: interleaved attn/pyramid levels 0..3 + final combine --------
// Phase order (in-place pyramid destroys half of level l when building l+1):
//   stage -> attn0 (y0 in regs) -> pyr1 -> attn1 -> pyr2 -> attn2 -> pyr3
//   -> attn3 -> combine.  Barriers between all phases.
__global__ __launch_bounds__(256, 1) void fused03_kernel(
    const unsigned short* __restrict__ qp, const unsigned short* __restrict__ kp,
    const unsigned short* __restrict__ vp, const unsigned short* __restrict__ yall,
    const float* __restrict__ aall, __hip_bfloat16* __restrict__ Ub) {
  __shared__ __align__(16) unsigned short qs[256 * 64];
  __shared__ __align__(16) unsigned short ks[256 * 64];
  __shared__ __align__(16) unsigned short vs[256 * 64];
  __shared__ unsigned short ylds[224 * 72];  // y1: 0-127, y2: 128-191, y3: 192-223
  __shared__ float alds[480];                // a1:0-127 a2:128-191 a3:192-223 a0:224-479
  __shared__ __align__(16) unsigned short vT[4][64 * 24];

  const int tid = threadIdx.x;
  const int w = tid >> 6, lane = tid & 63;
  const int m = lane & 15, q = lane >> 4;
  const int c = blockIdx.x, bh = blockIdx.y;
  const size_t base = (size_t)bh * ROWS_PER_BH;
  const size_t g0 = (base + c * 256) * 64;

  // swizzled-position index: short d of row r lives at chunk (d>>3)^(r&7)
  auto sidx = [](int r, int d) {
    return r * 64 + (((d >> 3) ^ (r & 7)) << 3) + (d & 7);
  };
  unsigned short* vtw = vT[w];

  // ---- stage level-0 chunk (pre-swizzled global source, linear LDS dest)
  {
    const int srow = tid >> 3;                    // 0..31 per issue
    const int sch = (tid & 7) ^ (srow & 7);
    const size_t gofs = (size_t)srow * 64 + sch * 8;
#pragma unroll
    for (int it = 0; it < 8; it++) {
      const size_t gi = g0 + (size_t)it * 2048 + gofs;
      g2lds16(qp + gi, &qs[it * 2048 + tid * 8]);
      g2lds16(kp + gi, &ks[it * 2048 + tid * 8]);
      g2lds16(vp + gi, &vs[it * 2048 + tid * 8]);
    }
  }
  __syncthreads();

  // attn for one 16x16 block at `level` (sibling flip iff level>0).
  // Returns row-sum a (broadcast); leaves y fragments in yout[4].
  auto attn_block = [&](int level, int blk, bool flip, floatx4 yout[4]) -> float {
    const int kb = flip ? (blk ^ 1) : blk;
    const int Rq = (blk * 16 + m) << level;
    const int Rk = (kb * 16 + m) << level;
    const bf16x8 ka0 = *(const bf16x8*)&ks[sidx(Rk, q * 8)];
    const bf16x8 ka1 = *(const bf16x8*)&ks[sidx(Rk, 32 + q * 8)];
    const bf16x8 qb0 = *(const bf16x8*)&qs[sidx(Rq, q * 8)];
    const bf16x8 qb1 = *(const bf16x8*)&qs[sidx(Rq, 32 + q * 8)];
    const ushortx8 v0 = *(const ushortx8*)&vs[sidx(Rq, q * 16)];
    const ushortx8 v1 = *(const ushortx8*)&vs[sidx(Rq, q * 16 + 8)];
#pragma unroll
    for (int j = 0; j < 8; j++) vtw[(q * 16 + j) * 24 + m] = v0[j];
#pragma unroll
    for (int j = 0; j < 8; j++) vtw[(q * 16 + 8 + j) * 24 + m] = v1[j];

    floatx4 s = (floatx4){0.f, 0.f, 0.f, 0.f};
    s = __builtin_amdgcn_mfma_f32_16x16x32_bf16(ka0, qb0, s, 0, 0, 0);
    s = __builtin_amdgcn_mfma_f32_16x16x32_bf16(ka1, qb1, s, 0, 0, 0);

    unsigned short pb0 = f2bu(__expf(s[0])), pb1 = f2bu(__expf(s[1]));
    unsigned short pb2 = f2bu(__expf(s[2])), pb3 = f2bu(__expf(s[3]));
    float asum = bu2f(pb0) + bu2f(pb1) + bu2f(pb2) + bu2f(pb3);
    asum += __shfl_xor(asum, 16, 64);
    asum += __shfl_xor(asum, 32, 64);

    unsigned int d0 = (unsigned int)pb0 | ((unsigned int)pb1 << 16);
    unsigned int d1 = (unsigned int)pb2 | ((unsigned int)pb3 << 16);
    const int s0l = m + 32 * (q & 1);
    unsigned int u0 = __shfl(d0, s0l, 64);
    unsigned int u1 = __shfl(d1, s0l, 64);
    unsigned int u2 = __shfl(d0, s0l + 16, 64);
    unsigned int u3 = __shfl(d1, s0l + 16, 64);
    union { uintx4 i; bf16x8 b; } pau;
    pau.i = (q < 2) ? (uintx4){u0, u1, u2, u3} : (uintx4){0u, 0u, 0u, 0u};
    const bf16x8 pa = pau.b;

#pragma unroll
    for (int cc = 0; cc < 4; cc++) {
      union { uintx4 i; bf16x8 b; } bvu;
      bvu.i = (uintx4){0u, 0u, 0u, 0u};
      if (q < 2) bvu.b = *(const bf16x8*)&vtw[(cc * 16 + m) * 24 + q * 8];
      floatx4 y = (floatx4){0.f, 0.f, 0.f, 0.f};
      y = __builtin_amdgcn_mfma_f32_16x16x32_bf16(pa, bvu.b, y, 0, 0, 0);
      yout[cc] = y;
    }
    return asum;
  };

  // in-place pyramid level l from level l-1 (swizzle-aware positions)
  auto pyr = [&](int l) {
    const int nOut = 256 >> l;
    for (int e = tid; e < nOut * 32; e += 256) {
      const int i = e >> 5, dp = (e & 31) * 2;
      const int ra = i << l, rb = ra + (1 << (l - 1));
      const int ia = sidx(ra, dp), ib = sidx(rb, dp);
      unsigned short q0 = f2bu(0.5f * (bu2f(qs[ia]) + bu2f(qs[ib])));
      unsigned short q1 = f2bu(0.5f * (bu2f(qs[ia + 1]) + bu2f(qs[ib + 1])));
      unsigned short k0 = f2bu(0.5f * (bu2f(ks[ia]) + bu2f(ks[ib])));
      unsigned short k1 = f2bu(0.5f * (bu2f(ks[ia + 1]) + bu2f(ks[ib + 1])));
      unsigned short v0 = f2bu(bu2f(vs[ia]) + bu2f(vs[ib]));
      unsigned short v1 = f2bu(bu2f(vs[ia + 1]) + bu2f(vs[ib + 1]));
      qs[ia] = q0; qs[ia + 1] = q1;
      ks[ia] = k0; ks[ia + 1] = k1;
      vs[ia] = v0; vs[ia + 1] = v1;
    }
  };

  // ---- attn level 0 (16 blocks over 4 waves), y0 kept in registers
  floatx4 y0reg[4][4];
#pragma unroll
  for (int t = 0; t < 4; t++) {
    const int blk = w + t * 4;
    float a0 = attn_block(0, blk, false, y0reg[t]);
    if (q == 0) alds[224 + blk * 16 + m] = a0;
  }
  __syncthreads();

  // ---- levels 1..3: build, then attend (write y to ylds, a to alds)
  pyr(1);
  __syncthreads();
  {
    floatx4 yt[4];
#pragma unroll
    for (int t = 0; t < 2; t++) {
      const int blk = w + t * 4;       // 8 blocks / 4 waves
      float a = attn_block(1, blk, true, yt);
      if (q == 0) alds[blk * 16 + m] = a;
#pragma unroll
      for (int cc = 0; cc < 4; cc++)
#pragma unroll
        for (int r = 0; r < 4; r++)
          ylds[(blk * 16 + q * 4 + r) * 72 + cc * 16 + m] = f2bu(yt[cc][r]);
    }
  }
  __syncthreads();
  pyr(2);
  __syncthreads();
  {
    floatx4 yt[4];
    const int blk = w;                 // 4 blocks / 4 waves
    float a = attn_block(2, blk, true, yt);
    if (q == 0) alds[128 + blk * 16 + m] = a;
#pragma unroll
    for (int cc = 0; cc < 4; cc++)
#pragma unroll
      for (int r = 0; r < 4; r++)
        ylds[(128 + blk * 16 + q * 4 + r) * 72 + cc * 16 + m] = f2bu(yt[cc][r]);
  }
  __syncthreads();
  pyr(3);
  __syncthreads();
  if (w < 2) {
    floatx4 yt[4];
    const int blk = w;                 // 2 blocks on waves 0,1
    float a = attn_block(3, blk, true, yt);
    if (q == 0) alds[192 + blk * 16 + m] = a;
#pragma unroll
    for (int cc = 0; cc < 4; cc++)
#pragma unroll
      for (int r = 0; r < 4; r++)
        ylds[(192 + blk * 16 + q * 4 + r) * 72 + cc * 16 + m] = f2bu(yt[cc][r]);
  }
  __syncthreads();

  // ---- final combine: U = (y0 + y1 + y2 + y3 + ycoarse) / (sum a + eps)
  const int bO = bh >> 3, hO = bh & 7;
#pragma unroll
  for (int t = 0; t < 4; t++) {
    const int blk = w + t * 4;
    const int i4 = c * 16 + blk;
    const size_t r4 = base + 7680 + i4;
    const size_t r5 = base + 7936 + (i4 >> 1);
    const size_t r6 = base + 8064 + (i4 >> 2);
    const size_t r7 = base + 8128 + (i4 >> 3);
    const float acoarse = aall[r4] + aall[r5] + aall[r6] + aall[r7];

    float inv[4];
#pragma unroll
    for (int r = 0; r < 4; r++) {
      const int row = blk * 16 + q * 4 + r;
      const float atot = alds[224 + row] + alds[row >> 1] +
                         alds[128 + (row >> 2)] + alds[192 + (row >> 3)] +
                         acoarse + 1e-8f;
      inv[r] = 1.0f / atot;
    }

#pragma unroll
    for (int cc = 0; cc < 4; cc++) {
      const int col = cc * 16 + m;
      const float yc = bu2f(yall[r4 * 64 + col]) + bu2f(yall[r5 * 64 + col]) +
                       bu2f(yall[r6 * 64 + col]) + bu2f(yall[r7 * 64 + col]);
#pragma unroll
      for (int r = 0; r < 4; r++) {
        const int row = blk * 16 + q * 4 + r;
        const float num = y0reg[t][cc][r] + bu2f(ylds[(row >> 1) * 72 + col]) +
                          bu2f(ylds[(128 + (row >> 2)) * 72 + col]) +
                          bu2f(ylds[(192 + (row >> 3)) * 72 + col]) + yc;
        Ub[((size_t)bO * 4096 + c * 256 + row) * 512 + hO * 64 + col] =
            __float2bfloat16(num * inv[r]);
      }
    }
  }
}

// ---------------------------------------------------------------------------
extern "C" void kernel_launch(void* const* d_in, const int* in_sizes, int n_in,
                              void* d_out, int out_size, void* d_ws, size_t ws_size,
                              hipStream_t stream) {
  const float* x     = (const float*)d_in[0];  // [4,4096,1024]
  const float* w_qkv = (const float*)d_in[1];  // [1536,1024]
  const float* w_out = (const float*)d_in[2];  // [1024,512]
  const float* b_out = (const float*)d_in[3];  // [1024]
  float* out = (float*)d_out;

  char* ws = (char*)d_ws;
  __hip_bfloat16* xb    = (__hip_bfloat16*)(ws + 0);           // 33554432 B
  __hip_bfloat16* wqkvb = (__hip_bfloat16*)(ws + 33554432);    //  3145728 B
  __hip_bfloat16* wob   = (__hip_bfloat16*)(ws + 36700160);    //  1048576 B
  __hip_bfloat16* qp    = (__hip_bfloat16*)(ws + 37748736);    // 33423360 B
  __hip_bfloat16* kp    = (__hip_bfloat16*)(ws + 71172096);    // 33423360 B
  __hip_bfloat16* vp    = (__hip_bfloat16*)(ws + 104595456);   // 33423360 B
  __hip_bfloat16* yall  = (__hip_bfloat16*)(ws + 138018816);   // 33423360 B
  float* aall           = (float*)(ws + 171442176);            //  1044480 B
  __hip_bfloat16* Ub    = (__hip_bfloat16*)(ws + 172486656);   // 16777216 B

  // 1) converts (single launch)
  f2b3_kernel<<<18432, 256, 0, stream>>>(x, w_qkv, w_out, xb, wqkvb, wob);

  // 2) qkv projection + level-0 scatter + level-4 emission
  gemm_qkv_kernel<<<dim3(128, 12), 256, 0, stream>>>(
      (const unsigned short*)xb, (const unsigned short*)wqkvb, qp, kp, vp);

  // 3) coarse pyramid (levels 5..7 from level 4)
  pyramid47_kernel<<<32, 256, 0, stream>>>(qp, kp, vp);

  // 4) coarse attention (levels 4..7) -> yall/aall
  attn47_kernel<<<dim3(8, 32), 256, 0, stream>>>(
      (const unsigned short*)qp, (const unsigned short*)kp,
      (const unsigned short*)vp, yall, aall);

  // 5) fused levels 0..3 pyramid + attn + final combine -> Ub
  fused03_kernel<<<dim3(16, 32), 256, 0, stream>>>(
      (const unsigned short*)qp, (const unsigned short*)kp,
      (const unsigned short*)vp, (const unsigned short*)yall, aall, Ub);

  // 6) out projection + bias
  gemm_out_kernel<<<dim3(128, 8), 256, 0, stream>>>(
      (const unsigned short*)Ub, (const unsigned short*)wob, b_out, out);
}

// Round 6
// 247.106 us; speedup vs baseline: 1.1558x; 1.0639x over previous
//
#include <hip/hip_runtime.h>
#include <hip/hip_bf16.h>

// ---------------------------------------------------------------------------
// HAttention1D: B=4 N=4096 DIM=1024 HEADS=8 DH=64 BSZ=16, 8 levels (0..7)
//  1) f2b3: x, w_qkv, w_out -> bf16 (single launch)
//  2) gemm_qkv (128x128 MFMA): qkv = x@w_qkv^T; epilogue scatters level-0
//     AND emits level-4 rows directly from f32 accumulators (cross-quad sum)
//  3) coarse47 (per bh, 512 thr): stage level-4 to swizzled LDS, interleaved
//     attn-l / build-(l+1) for global levels 4..7 -> yall/aall (lvl 5-7 qkv
//     never touch HBM)
//  4) fused03 (per (bh, 256-row chunk), 512 thr): stage level-0 qkv to
//     swizzled LDS, interleaved attn0(y0 regs) -> pyr1 -> attn1 -> pyr2 ->
//     attn2 -> pyr3 -> attn3 -> fused final combine -> Ub
//  5) gemm_out (128x128 MFMA): out = U @ w_out^T + b_out
// ---------------------------------------------------------------------------

typedef __bf16 bf16x8 __attribute__((ext_vector_type(8)));
typedef float floatx4 __attribute__((ext_vector_type(4)));
typedef unsigned short ushortx8 __attribute__((ext_vector_type(8)));
typedef unsigned int uintx4 __attribute__((ext_vector_type(4)));

#define ROWS_PER_BH 8160  // 4096+2048+1024+512+256+128+64+32

__device__ __forceinline__ void g2lds16(const void* g, void* l) {
  __builtin_amdgcn_global_load_lds(
      (const __attribute__((address_space(1))) void*)g,
      (__attribute__((address_space(3))) void*)l, 16, 0, 0);
}

__device__ __forceinline__ unsigned short f2bu(float x) {
  __hip_bfloat16 h = __float2bfloat16(x);
  return *(unsigned short*)&h;
}
__device__ __forceinline__ float bu2f(unsigned short u) {
  __hip_bfloat16 h = *(__hip_bfloat16*)&u;
  return __bfloat162float(h);
}

// ---- fp32 -> bf16 convert, all three tensors in one launch ----------------
__global__ __launch_bounds__(256) void f2b3_kernel(const float* __restrict__ x,
                                                   const float* __restrict__ wq,
                                                   const float* __restrict__ wo,
                                                   __hip_bfloat16* __restrict__ xb,
                                                   __hip_bfloat16* __restrict__ wqb,
                                                   __hip_bfloat16* __restrict__ wob) {
  int i0 = (blockIdx.x * 256 + threadIdx.x) * 4;
  const float* s;
  __hip_bfloat16* d;
  if (i0 < 16777216) {
    s = x; d = xb;
  } else if (i0 < 16777216 + 1572864) {
    s = wq + (i0 - 16777216); d = wqb + (i0 - 16777216);
    float4 v = *(const float4*)s;
    d[0] = __float2bfloat16(v.x); d[1] = __float2bfloat16(v.y);
    d[2] = __float2bfloat16(v.z); d[3] = __float2bfloat16(v.w);
    return;
  } else {
    s = wo + (i0 - 16777216 - 1572864); d = wob + (i0 - 16777216 - 1572864);
    float4 v = *(const float4*)s;
    d[0] = __float2bfloat16(v.x); d[1] = __float2bfloat16(v.y);
    d[2] = __float2bfloat16(v.z); d[3] = __float2bfloat16(v.w);
    return;
  }
  float4 v = *(const float4*)(s + i0);
  d[i0 + 0] = __float2bfloat16(v.x);
  d[i0 + 1] = __float2bfloat16(v.y);
  d[i0 + 2] = __float2bfloat16(v.z);
  d[i0 + 3] = __float2bfloat16(v.w);
}

// ---- shared GEMM core: 128x128 tile, BK=64, XOR-swizzled LDS --------------
template <int K>
__device__ __forceinline__ void gemm_core(const unsigned short* __restrict__ A,
                                          const unsigned short* __restrict__ B,
                                          unsigned short* ldsA, unsigned short* ldsB,
                                          int tM, int tN, floatx4 acc[4][4]) {
  const int tid = threadIdx.x;
  const int lane = tid & 63, w = tid >> 6;
  const int wm = w >> 1, wn = w & 1;
  const int lr = lane >> 3;            // row-within-8 for staging
  const int gch = (lane & 7) ^ lr;     // XOR-swizzled global chunk
  const unsigned short* Ag = A + (size_t)(tM + w * 32 + lr) * K + gch * 8;
  const unsigned short* Bg = B + (size_t)(tN + w * 32 + lr) * K + gch * 8;
  unsigned short* lA = &ldsA[w * 2048 + lane * 8];
  unsigned short* lB = &ldsB[w * 2048 + lane * 8];

  const int rA = wm * 64 + (lane & 15);
  const int rB = wn * 64 + (lane & 15);
  const int quad = lane >> 4;
  const int sw = lane & 7;             // fragment row & 7

  for (int kt = 0; kt < K; kt += 64) {
    __syncthreads();
#pragma unroll
    for (int c = 0; c < 4; c++) {
      g2lds16(Ag + (size_t)(c * 8) * K + kt, lA + c * 512);
      g2lds16(Bg + (size_t)(c * 8) * K + kt, lB + c * 512);
    }
    __syncthreads();
#pragma unroll
    for (int kk = 0; kk < 2; kk++) {
      bf16x8 af[4], bv[4];
#pragma unroll
      for (int i = 0; i < 4; i++)
        af[i] = *(const bf16x8*)&ldsA[(rA + i * 16) * 64 + (((kk * 4 + quad) ^ sw) * 8)];
#pragma unroll
      for (int j = 0; j < 4; j++)
        bv[j] = *(const bf16x8*)&ldsB[(rB + j * 16) * 64 + (((kk * 4 + quad) ^ sw) * 8)];
#pragma unroll
      for (int i = 0; i < 4; i++)
#pragma unroll
        for (int j = 0; j < 4; j++)
          acc[i][j] = __builtin_amdgcn_mfma_f32_16x16x32_bf16(af[i], bv[j], acc[i][j], 0, 0, 0);
    }
  }
}

// ---- GEMM1: qkv = x[16384,1024] @ w_qkv[1536,1024]^T ----------------------
// epilogue: scatter level-0 + emit level-4 rows (mean/mean/sum of 16 rows)
__global__ __launch_bounds__(256) void gemm_qkv_kernel(
    const unsigned short* __restrict__ A,   // xb [16384,1024] bf16
    const unsigned short* __restrict__ B,   // wqkvb [1536,1024] bf16
    __hip_bfloat16* __restrict__ qp, __hip_bfloat16* __restrict__ kp,
    __hip_bfloat16* __restrict__ vp) {
  __shared__ unsigned short ldsA[128 * 64];
  __shared__ unsigned short ldsB[128 * 64];
  const int lane = threadIdx.x & 63, w = threadIdx.x >> 6;
  const int wm = w >> 1, wn = w & 1;
  const int tM = blockIdx.x * 128, tN = blockIdx.y * 128;

  floatx4 acc[4][4];
#pragma unroll
  for (int i = 0; i < 4; i++)
#pragma unroll
    for (int j = 0; j < 4; j++) acc[i][j] = (floatx4){0.f, 0.f, 0.f, 0.f};

  gemm_core<1024>(A, B, ldsA, ldsB, tM, tN, acc);

  // epilogue: C/D layout col=lane&15, row=(lane>>4)*4+r  [verified m89]
  const int quad = lane >> 4, m15 = lane & 15;
#pragma unroll
  for (int i = 0; i < 4; i++) {
#pragma unroll
    for (int j = 0; j < 4; j++) {
      const int c = tN + wn * 64 + j * 16 + m15;
      const int tensor = c >> 9;         // 0=q 1=k 2=v
      const int rem = c & 511;
      const int h = rem >> 6, d = rem & 63;
      __hip_bfloat16* dstbuf = (tensor == 0) ? qp : ((tensor == 1) ? kp : vp);
      const float scale = (tensor == 0) ? 0.125f : 1.0f;  // DH^-0.5
#pragma unroll
      for (int r = 0; r < 4; r++) {
        const int m = tM + wm * 64 + i * 16 + quad * 4 + r;
        const int b = m >> 12, n = m & 4095;
        size_t dst = ((size_t)(b * 8 + h) * ROWS_PER_BH + n) * 64 + d;
        dstbuf[dst] = __float2bfloat16(acc[i][j][r] * scale);
      }
      // level-4 row: sum of 16 consecutive rows (in-lane 4 + cross-quad)
      float s4 = acc[i][j][0] + acc[i][j][1] + acc[i][j][2] + acc[i][j][3];
      s4 += __shfl_xor(s4, 16, 64);
      s4 += __shfl_xor(s4, 32, 64);
      if (quad == 0) {
        const int mrow = tM + wm * 64 + i * 16;     // multiple of 16
        const int b = mrow >> 12, n4 = (mrow & 4095) >> 4;
        // q: mean*0.125; k: mean; v: sum
        const float val = (tensor == 0) ? s4 * (0.125f / 16.f)
                         : ((tensor == 1) ? s4 * (1.f / 16.f) : s4);
        dstbuf[((size_t)(b * 8 + h) * ROWS_PER_BH + 7680 + n4) * 64 + d] =
            __float2bfloat16(val);
      }
    }
  }
}

// ---- GEMM2: out = U[16384,512] @ w_out[1024,512]^T + b_out ----------------
__global__ __launch_bounds__(256) void gemm_out_kernel(
    const unsigned short* __restrict__ A,   // Ub [16384,512] bf16
    const unsigned short* __restrict__ B,   // wob [1024,512] bf16
    const float* __restrict__ bias, float* __restrict__ out) {
  __shared__ unsigned short ldsA[128 * 64];
  __shared__ unsigned short ldsB[128 * 64];
  const int lane = threadIdx.x & 63, w = threadIdx.x >> 6;
  const int wm = w >> 1, wn = w & 1;
  const int tM = blockIdx.x * 128, tN = blockIdx.y * 128;

  floatx4 acc[4][4];
#pragma unroll
  for (int i = 0; i < 4; i++)
#pragma unroll
    for (int j = 0; j < 4; j++) acc[i][j] = (floatx4){0.f, 0.f, 0.f, 0.f};

  gemm_core<512>(A, B, ldsA, ldsB, tM, tN, acc);

  const int quad = lane >> 4;
#pragma unroll
  for (int i = 0; i < 4; i++) {
#pragma unroll
    for (int j = 0; j < 4; j++) {
      const int c = tN + wn * 64 + j * 16 + (lane & 15);
      const float bb = bias[c];
#pragma unroll
      for (int r = 0; r < 4; r++) {
        const int m = tM + wm * 64 + i * 16 + quad * 4 + r;
        out[(size_t)m * 1024 + c] = acc[i][j][r] + bb;
      }
    }
  }
}

// ---- coarse47: per bh (512 thr): levels 4..7 attn+pyramid in LDS ----------
// stage level-4 (256 rows, swizzled) -> attn4 -> pyr5 -> attn5 -> pyr6 ->
// attn6 -> pyr7 -> attn7; y/a straight to global. Levels 5-7 qkv never
// touch HBM.
__global__ __launch_bounds__(512, 1) void coarse47_kernel(
    const unsigned short* __restrict__ qp, const unsigned short* __restrict__ kp,
    const unsigned short* __restrict__ vp, __hip_bfloat16* __restrict__ yall,
    float* __restrict__ aall) {
  __shared__ __align__(16) unsigned short qs[256 * 64];
  __shared__ __align__(16) unsigned short ks[256 * 64];
  __shared__ __align__(16) unsigned short vs[256 * 64];
  __shared__ __align__(16) unsigned short vT[8][64 * 24];

  const int tid = threadIdx.x;
  const int w = tid >> 6, lane = tid & 63;
  const int m = lane & 15, q = lane >> 4;
  const int bh = blockIdx.x;
  const size_t base = (size_t)bh * ROWS_PER_BH;
  const size_t g0 = (base + 7680) * 64;

  auto sidx = [](int r, int d) {
    return r * 64 + (((d >> 3) ^ (r & 7)) << 3) + (d & 7);
  };
  unsigned short* vtw = vT[w];

  // stage (pre-swizzled global source, linear LDS dest): 4 issues/tensor
  {
    const int srow = tid >> 3;                    // 0..63
    const int sch = (tid & 7) ^ (srow & 7);
    const size_t gofs = (size_t)srow * 64 + sch * 8;
#pragma unroll
    for (int it = 0; it < 4; it++) {
      const size_t gi = g0 + (size_t)it * 4096 + gofs;
      g2lds16(qp + gi, &qs[it * 4096 + tid * 8]);
      g2lds16(kp + gi, &ks[it * 4096 + tid * 8]);
      g2lds16(vp + gi, &vs[it * 4096 + tid * 8]);
    }
  }
  __syncthreads();

  auto attn_block = [&](int level, int blk, bool flip, floatx4 yout[4]) -> float {
    const int kb = flip ? (blk ^ 1) : blk;
    const int Rq = (blk * 16 + m) << level;
    const int Rk = (kb * 16 + m) << level;
    const bf16x8 ka0 = *(const bf16x8*)&ks[sidx(Rk, q * 8)];
    const bf16x8 ka1 = *(const bf16x8*)&ks[sidx(Rk, 32 + q * 8)];
    const bf16x8 qb0 = *(const bf16x8*)&qs[sidx(Rq, q * 8)];
    const bf16x8 qb1 = *(const bf16x8*)&qs[sidx(Rq, 32 + q * 8)];
    const ushortx8 v0 = *(const ushortx8*)&vs[sidx(Rq, q * 16)];
    const ushortx8 v1 = *(const ushortx8*)&vs[sidx(Rq, q * 16 + 8)];
#pragma unroll
    for (int j = 0; j < 8; j++) vtw[(q * 16 + j) * 24 + m] = v0[j];
#pragma unroll
    for (int j = 0; j < 8; j++) vtw[(q * 16 + 8 + j) * 24 + m] = v1[j];

    floatx4 s = (floatx4){0.f, 0.f, 0.f, 0.f};
    s = __builtin_amdgcn_mfma_f32_16x16x32_bf16(ka0, qb0, s, 0, 0, 0);
    s = __builtin_amdgcn_mfma_f32_16x16x32_bf16(ka1, qb1, s, 0, 0, 0);

    unsigned short pb0 = f2bu(__expf(s[0])), pb1 = f2bu(__expf(s[1]));
    unsigned short pb2 = f2bu(__expf(s[2])), pb3 = f2bu(__expf(s[3]));
    float asum = bu2f(pb0) + bu2f(pb1) + bu2f(pb2) + bu2f(pb3);
    asum += __shfl_xor(asum, 16, 64);
    asum += __shfl_xor(asum, 32, 64);

    unsigned int d0 = (unsigned int)pb0 | ((unsigned int)pb1 << 16);
    unsigned int d1 = (unsigned int)pb2 | ((unsigned int)pb3 << 16);
    const int s0l = m + 32 * (q & 1);
    unsigned int u0 = __shfl(d0, s0l, 64);
    unsigned int u1 = __shfl(d1, s0l, 64);
    unsigned int u2 = __shfl(d0, s0l + 16, 64);
    unsigned int u3 = __shfl(d1, s0l + 16, 64);
    union { uintx4 i; bf16x8 b; } pau;
    pau.i = (q < 2) ? (uintx4){u0, u1, u2, u3} : (uintx4){0u, 0u, 0u, 0u};
    const bf16x8 pa = pau.b;

#pragma unroll
    for (int cc = 0; cc < 4; cc++) {
      union { uintx4 i; bf16x8 b; } bvu;
      bvu.i = (uintx4){0u, 0u, 0u, 0u};
      if (q < 2) bvu.b = *(const bf16x8*)&vtw[(cc * 16 + m) * 24 + q * 8];
      floatx4 y = (floatx4){0.f, 0.f, 0.f, 0.f};
      y = __builtin_amdgcn_mfma_f32_16x16x32_bf16(pa, bvu.b, y, 0, 0, 0);
      yout[cc] = y;
    }
    return asum;
  };

  auto pyr = [&](int l) {
    const int nOut = 256 >> l;
    for (int e = tid; e < nOut * 32; e += 512) {
      const int i = e >> 5, dp = (e & 31) * 2;
      const int ra = i << l, rb = ra + (1 << (l - 1));
      const int ia = sidx(ra, dp), ib = sidx(rb, dp);
      unsigned short q0 = f2bu(0.5f * (bu2f(qs[ia]) + bu2f(qs[ib])));
      unsigned short q1 = f2bu(0.5f * (bu2f(qs[ia + 1]) + bu2f(qs[ib + 1])));
      unsigned short k0 = f2bu(0.5f * (bu2f(ks[ia]) + bu2f(ks[ib])));
      unsigned short k1 = f2bu(0.5f * (bu2f(ks[ia + 1]) + bu2f(ks[ib + 1])));
      unsigned short v0 = f2bu(bu2f(vs[ia]) + bu2f(vs[ib]));
      unsigned short v1 = f2bu(bu2f(vs[ia + 1]) + bu2f(vs[ib + 1]));
      qs[ia] = q0; qs[ia + 1] = q1;
      ks[ia] = k0; ks[ia + 1] = k1;
      vs[ia] = v0; vs[ia + 1] = v1;
    }
  };

  auto emit = [&](int ro, int blk, const floatx4 yt[4], float a) {
    const size_t arow = base + ro + blk * 16;
    if (q == 0) aall[arow + m] = a;
#pragma unroll
    for (int cc = 0; cc < 4; cc++)
#pragma unroll
      for (int r = 0; r < 4; r++)
        yall[(arow + q * 4 + r) * 64 + cc * 16 + m] = __float2bfloat16(yt[cc][r]);
  };

  // level 4 (local 0): 16 blocks over 8 waves
  {
    floatx4 yt[4];
#pragma unroll
    for (int t = 0; t < 2; t++) {
      const int blk = w + t * 8;
      float a = attn_block(0, blk, true, yt);
      emit(7680, blk, yt, a);
    }
  }
  __syncthreads();
  pyr(1);
  __syncthreads();
  // level 5 (local 1): 8 blocks
  {
    floatx4 yt[4];
    float a = attn_block(1, w, true, yt);
    emit(7936, w, yt, a);
  }
  __syncthreads();
  pyr(2);
  __syncthreads();
  // level 6 (local 2): 4 blocks
  if (w < 4) {
    floatx4 yt[4];
    float a = attn_block(2, w, true, yt);
    emit(8064, w, yt, a);
  }
  __syncthreads();
  pyr(3);
  __syncthreads();
  // level 7 (local 3): 2 blocks
  if (w < 2) {
    floatx4 yt[4];
    float a = attn_block(3, w, true, yt);
    emit(8128, w, yt, a);
  }
}

// ---- fused03 (512 thr): interleaved attn/pyramid levels 0..3 + combine ----
// stage -> attn0 (y0 in regs) -> pyr1 -> attn1 -> pyr2 -> attn2 -> pyr3
// -> attn3 -> combine.  Barriers between all phases.
__global__ __launch_bounds__(512, 1) void fused03_kernel(
    const unsigned short* __restrict__ qp, const unsigned short* __restrict__ kp,
    const unsigned short* __restrict__ vp, const unsigned short* __restrict__ yall,
    const float* __restrict__ aall, __hip_bfloat16* __restrict__ Ub) {
  __shared__ __align__(16) unsigned short qs[256 * 64];
  __shared__ __align__(16) unsigned short ks[256 * 64];
  __shared__ __align__(16) unsigned short vs[256 * 64];
  __shared__ unsigned short ylds[224 * 72];  // y1: 0-127, y2: 128-191, y3: 192-223
  __shared__ float alds[480];                // a1:0-127 a2:128-191 a3:192-223 a0:224-479
  __shared__ __align__(16) unsigned short vT[8][64 * 24];

  const int tid = threadIdx.x;
  const int w = tid >> 6, lane = tid & 63;
  const int m = lane & 15, q = lane >> 4;
  const int c = blockIdx.x, bh = blockIdx.y;
  const size_t base = (size_t)bh * ROWS_PER_BH;
  const size_t g0 = (base + c * 256) * 64;

  auto sidx = [](int r, int d) {
    return r * 64 + (((d >> 3) ^ (r & 7)) << 3) + (d & 7);
  };
  unsigned short* vtw = vT[w];

  // stage (pre-swizzled global source, linear LDS dest): 4 issues/tensor
  {
    const int srow = tid >> 3;                    // 0..63
    const int sch = (tid & 7) ^ (srow & 7);
    const size_t gofs = (size_t)srow * 64 + sch * 8;
#pragma unroll
    for (int it = 0; it < 4; it++) {
      const size_t gi = g0 + (size_t)it * 4096 + gofs;
      g2lds16(qp + gi, &qs[it * 4096 + tid * 8]);
      g2lds16(kp + gi, &ks[it * 4096 + tid * 8]);
      g2lds16(vp + gi, &vs[it * 4096 + tid * 8]);
    }
  }
  __syncthreads();

  auto attn_block = [&](int level, int blk, bool flip, floatx4 yout[4]) -> float {
    const int kb = flip ? (blk ^ 1) : blk;
    const int Rq = (blk * 16 + m) << level;
    const int Rk = (kb * 16 + m) << level;
    const bf16x8 ka0 = *(const bf16x8*)&ks[sidx(Rk, q * 8)];
    const bf16x8 ka1 = *(const bf16x8*)&ks[sidx(Rk, 32 + q * 8)];
    const bf16x8 qb0 = *(const bf16x8*)&qs[sidx(Rq, q * 8)];
    const bf16x8 qb1 = *(const bf16x8*)&qs[sidx(Rq, 32 + q * 8)];
    const ushortx8 v0 = *(const ushortx8*)&vs[sidx(Rq, q * 16)];
    const ushortx8 v1 = *(const ushortx8*)&vs[sidx(Rq, q * 16 + 8)];
#pragma unroll
    for (int j = 0; j < 8; j++) vtw[(q * 16 + j) * 24 + m] = v0[j];
#pragma unroll
    for (int j = 0; j < 8; j++) vtw[(q * 16 + 8 + j) * 24 + m] = v1[j];

    floatx4 s = (floatx4){0.f, 0.f, 0.f, 0.f};
    s = __builtin_amdgcn_mfma_f32_16x16x32_bf16(ka0, qb0, s, 0, 0, 0);
    s = __builtin_amdgcn_mfma_f32_16x16x32_bf16(ka1, qb1, s, 0, 0, 0);

    unsigned short pb0 = f2bu(__expf(s[0])), pb1 = f2bu(__expf(s[1]));
    unsigned short pb2 = f2bu(__expf(s[2])), pb3 = f2bu(__expf(s[3]));
    float asum = bu2f(pb0) + bu2f(pb1) + bu2f(pb2) + bu2f(pb3);
    asum += __shfl_xor(asum, 16, 64);
    asum += __shfl_xor(asum, 32, 64);

    unsigned int d0 = (unsigned int)pb0 | ((unsigned int)pb1 << 16);
    unsigned int d1 = (unsigned int)pb2 | ((unsigned int)pb3 << 16);
    const int s0l = m + 32 * (q & 1);
    unsigned int u0 = __shfl(d0, s0l, 64);
    unsigned int u1 = __shfl(d1, s0l, 64);
    unsigned int u2 = __shfl(d0, s0l + 16, 64);
    unsigned int u3 = __shfl(d1, s0l + 16, 64);
    union { uintx4 i; bf16x8 b; } pau;
    pau.i = (q < 2) ? (uintx4){u0, u1, u2, u3} : (uintx4){0u, 0u, 0u, 0u};
    const bf16x8 pa = pau.b;

#pragma unroll
    for (int cc = 0; cc < 4; cc++) {
      union { uintx4 i; bf16x8 b; } bvu;
      bvu.i = (uintx4){0u, 0u, 0u, 0u};
      if (q < 2) bvu.b = *(const bf16x8*)&vtw[(cc * 16 + m) * 24 + q * 8];
      floatx4 y = (floatx4){0.f, 0.f, 0.f, 0.f};
      y = __builtin_amdgcn_mfma_f32_16x16x32_bf16(pa, bvu.b, y, 0, 0, 0);
      yout[cc] = y;
    }
    return asum;
  };

  auto pyr = [&](int l) {
    const int nOut = 256 >> l;
    for (int e = tid; e < nOut * 32; e += 512) {
      const int i = e >> 5, dp = (e & 31) * 2;
      const int ra = i << l, rb = ra + (1 << (l - 1));
      const int ia = sidx(ra, dp), ib = sidx(rb, dp);
      unsigned short q0 = f2bu(0.5f * (bu2f(qs[ia]) + bu2f(qs[ib])));
      unsigned short q1 = f2bu(0.5f * (bu2f(qs[ia + 1]) + bu2f(qs[ib + 1])));
      unsigned short k0 = f2bu(0.5f * (bu2f(ks[ia]) + bu2f(ks[ib])));
      unsigned short k1 = f2bu(0.5f * (bu2f(ks[ia + 1]) + bu2f(ks[ib + 1])));
      unsigned short v0 = f2bu(bu2f(vs[ia]) + bu2f(vs[ib]));
      unsigned short v1 = f2bu(bu2f(vs[ia + 1]) + bu2f(vs[ib + 1]));
      qs[ia] = q0; qs[ia + 1] = q1;
      ks[ia] = k0; ks[ia + 1] = k1;
      vs[ia] = v0; vs[ia + 1] = v1;
    }
  };

  // ---- attn level 0 (16 blocks over 8 waves), y0 kept in registers
  floatx4 y0reg[2][4];
#pragma unroll
  for (int t = 0; t < 2; t++) {
    const int blk = w + t * 8;
    float a0 = attn_block(0, blk, false, y0reg[t]);
    if (q == 0) alds[224 + blk * 16 + m] = a0;
  }
  __syncthreads();

  // ---- levels 1..3: build, then attend (write y to ylds, a to alds)
  pyr(1);
  __syncthreads();
  {
    floatx4 yt[4];
    const int blk = w;                 // 8 blocks / 8 waves
    float a = attn_block(1, blk, true, yt);
    if (q == 0) alds[blk * 16 + m] = a;
#pragma unroll
    for (int cc = 0; cc < 4; cc++)
#pragma unroll
      for (int r = 0; r < 4; r++)
        ylds[(blk * 16 + q * 4 + r) * 72 + cc * 16 + m] = f2bu(yt[cc][r]);
  }
  __syncthreads();
  pyr(2);
  __syncthreads();
  if (w < 4) {
    floatx4 yt[4];
    const int blk = w;                 // 4 blocks on waves 0..3
    float a = attn_block(2, blk, true, yt);
    if (q == 0) alds[128 + blk * 16 + m] = a;
#pragma unroll
    for (int cc = 0; cc < 4; cc++)
#pragma unroll
      for (int r = 0; r < 4; r++)
        ylds[(128 + blk * 16 + q * 4 + r) * 72 + cc * 16 + m] = f2bu(yt[cc][r]);
  }
  __syncthreads();
  pyr(3);
  __syncthreads();
  if (w < 2) {
    floatx4 yt[4];
    const int blk = w;                 // 2 blocks on waves 0,1
    float a = attn_block(3, blk, true, yt);
    if (q == 0) alds[192 + blk * 16 + m] = a;
#pragma unroll
    for (int cc = 0; cc < 4; cc++)
#pragma unroll
      for (int r = 0; r < 4; r++)
        ylds[(192 + blk * 16 + q * 4 + r) * 72 + cc * 16 + m] = f2bu(yt[cc][r]);
  }
  __syncthreads();

  // ---- final combine: U = (y0 + y1 + y2 + y3 + ycoarse) / (sum a + eps)
  const int bO = bh >> 3, hO = bh & 7;
#pragma unroll
  for (int t = 0; t < 2; t++) {
    const int blk = w + t * 8;
    const int i4 = c * 16 + blk;
    const size_t r4 = base + 7680 + i4;
    const size_t r5 = base + 7936 + (i4 >> 1);
    const size_t r6 = base + 8064 + (i4 >> 2);
    const size_t r7 = base + 8128 + (i4 >> 3);
    const float acoarse = aall[r4] + aall[r5] + aall[r6] + aall[r7];

    float inv[4];
#pragma unroll
    for (int r = 0; r < 4; r++) {
      const int row = blk * 16 + q * 4 + r;
      const float atot = alds[224 + row] + alds[row >> 1] +
                         alds[128 + (row >> 2)] + alds[192 + (row >> 3)] +
                         acoarse + 1e-8f;
      inv[r] = 1.0f / atot;
    }

#pragma unroll
    for (int cc = 0; cc < 4; cc++) {
      const int col = cc * 16 + m;
      const float yc = bu2f(yall[r4 * 64 + col]) + bu2f(yall[r5 * 64 + col]) +
                       bu2f(yall[r6 * 64 + col]) + bu2f(yall[r7 * 64 + col]);
#pragma unroll
      for (int r = 0; r < 4; r++) {
        const int row = blk * 16 + q * 4 + r;
        const float num = y0reg[t][cc][r] + bu2f(ylds[(row >> 1) * 72 + col]) +
                          bu2f(ylds[(128 + (row >> 2)) * 72 + col]) +
                          bu2f(ylds[(192 + (row >> 3)) * 72 + col]) + yc;
        Ub[((size_t)bO * 4096 + c * 256 + row) * 512 + hO * 64 + col] =
            __float2bfloat16(num * inv[r]);
      }
    }
  }
}

// ---------------------------------------------------------------------------
extern "C" void kernel_launch(void* const* d_in, const int* in_sizes, int n_in,
                              void* d_out, int out_size, void* d_ws, size_t ws_size,
                              hipStream_t stream) {
  const float* x     = (const float*)d_in[0];  // [4,4096,1024]
  const float* w_qkv = (const float*)d_in[1];  // [1536,1024]
  const float* w_out = (const float*)d_in[2];  // [1024,512]
  const float* b_out = (const float*)d_in[3];  // [1024]
  float* out = (float*)d_out;

  char* ws = (char*)d_ws;
  __hip_bfloat16* xb    = (__hip_bfloat16*)(ws + 0);           // 33554432 B
  __hip_bfloat16* wqkvb = (__hip_bfloat16*)(ws + 33554432);    //  3145728 B
  __hip_bfloat16* wob   = (__hip_bfloat16*)(ws + 36700160);    //  1048576 B
  __hip_bfloat16* qp    = (__hip_bfloat16*)(ws + 37748736);    // 33423360 B
  __hip_bfloat16* kp    = (__hip_bfloat16*)(ws + 71172096);    // 33423360 B
  __hip_bfloat16* vp    = (__hip_bfloat16*)(ws + 104595456);   // 33423360 B
  __hip_bfloat16* yall  = (__hip_bfloat16*)(ws + 138018816);   // 33423360 B
  float* aall           = (float*)(ws + 171442176);            //  1044480 B
  __hip_bfloat16* Ub    = (__hip_bfloat16*)(ws + 172486656);   // 16777216 B

  // 1) converts (single launch)
  f2b3_kernel<<<18432, 256, 0, stream>>>(x, w_qkv, w_out, xb, wqkvb, wob);

  // 2) qkv projection + level-0 scatter + level-4 emission
  gemm_qkv_kernel<<<dim3(128, 12), 256, 0, stream>>>(
      (const unsigned short*)xb, (const unsigned short*)wqkvb, qp, kp, vp);

  // 3) coarse levels 4..7: pyramid + attention fused, per bh
  coarse47_kernel<<<32, 512, 0, stream>>>(
      (const unsigned short*)qp, (const unsigned short*)kp,
      (const unsigned short*)vp, yall, aall);

  // 4) fused levels 0..3 pyramid + attn + final combine -> Ub
  fused03_kernel<<<dim3(16, 32), 512, 0, stream>>>(
      (const unsigned short*)qp, (const unsigned short*)kp,
      (const unsigned short*)vp, (const unsigned short*)yall, aall, Ub);

  // 5) out projection + bias
  gemm_out_kernel<<<dim3(128, 8), 256, 0, stream>>>(
      (const unsigned short*)Ub, (const unsigned short*)wob, b_out, out);
}